// Round 4
// baseline (547.197 us; speedup 1.0000x reference)
//
#include <hip/hip_runtime.h>

#define N_NODES 40000
#define N_EDGES 640000
#define N_REL   4
#define NBINS   (N_NODES * N_REL)   // 160000 (dst, rel) segments
#define EMB     128
#define HID     256
#define VOCAB   16
#define NB      4096

// ================= CSR build: histogram -> scan -> scatter =================

__global__ __launch_bounds__(256) void hist_kernel(const int* __restrict__ ei,
                                                   const int* __restrict__ et,
                                                   int* __restrict__ bins) {
    int e = blockIdx.x * blockDim.x + threadIdx.x;
    if (e < N_EDGES) {
        int dst = ei[N_EDGES + e];
        int r   = et[e];
        atomicAdd(&bins[dst * N_REL + r], 1);
    }
}

// block-local exclusive scan over 1024 bins/block (256 thr x 4), emit block sums
__global__ __launch_bounds__(256) void scanA_kernel(const int* __restrict__ bins,
                                                    int* __restrict__ ptr,
                                                    int* __restrict__ bsum) {
    __shared__ int wsum[4];
    int t    = threadIdx.x;
    int base = blockIdx.x * 1024 + t * 4;
    int v[4];
#pragma unroll
    for (int i = 0; i < 4; ++i) {
        int idx = base + i;
        v[i] = (idx < NBINS) ? bins[idx] : 0;
    }
    int tot  = v[0] + v[1] + v[2] + v[3];
    int lane = t & 63, w = t >> 6;
    int inc  = tot;
#pragma unroll
    for (int d = 1; d < 64; d <<= 1) {
        int n = __shfl_up(inc, d);
        if (lane >= d) inc += n;
    }
    if (lane == 63) wsum[w] = inc;
    __syncthreads();
    int woff = 0;
    for (int i = 0; i < w; ++i) woff += wsum[i];
    int run = woff + inc - tot;   // exclusive offset of this thread's 4 elems
#pragma unroll
    for (int i = 0; i < 4; ++i) {
        int idx = base + i;
        if (idx < NBINS) ptr[idx] = run;
        run += v[i];
    }
    if (t == 255) bsum[blockIdx.x] = woff + inc;
}

// single-block exclusive scan of the block sums (nblk <= 256)
__global__ __launch_bounds__(256) void scanB_kernel(const int* __restrict__ bsum,
                                                    int* __restrict__ boff, int nblk) {
    __shared__ int sh[256];
    int t = threadIdx.x;
    int v = (t < nblk) ? bsum[t] : 0;
    sh[t] = v;
    __syncthreads();
    for (int d = 1; d < 256; d <<= 1) {
        int n = (t >= d) ? sh[t - d] : 0;
        __syncthreads();
        sh[t] += n;
        __syncthreads();
    }
    if (t < nblk) boff[t] = sh[t] - v;   // exclusive
}

// add block offsets; init the scatter cursors; set ptr[NBINS] = E
__global__ __launch_bounds__(256) void scanC_kernel(int* __restrict__ ptr,
                                                    int* __restrict__ cur,
                                                    const int* __restrict__ boff) {
    int base = blockIdx.x * 1024 + threadIdx.x * 4;
    int off  = boff[blockIdx.x];
#pragma unroll
    for (int i = 0; i < 4; ++i) {
        int idx = base + i;
        if (idx < NBINS) {
            int p = ptr[idx] + off;
            ptr[idx] = p;
            cur[idx] = p;
        }
    }
    if (blockIdx.x == 0 && threadIdx.x == 0) ptr[NBINS] = N_EDGES;
}

__global__ __launch_bounds__(256) void scatter_kernel(const int* __restrict__ ei,
                                                      const int* __restrict__ et,
                                                      int* __restrict__ cur,
                                                      int* __restrict__ perm) {
    int e = blockIdx.x * blockDim.x + threadIdx.x;
    if (e < N_EDGES) {
        int src = ei[e];
        int dst = ei[N_EDGES + e];
        int r   = et[e];
        int pos = atomicAdd(&cur[dst * N_REL + r], 1);
        perm[pos] = src;
    }
}

// ============ segmented mean-aggregation: S[n,r,:] = mean x[src] ============
// one wave per node; lane owns 2 columns (float2); mean scale folded in.
__global__ __launch_bounds__(256) void agg_csr_kernel(const float* __restrict__ X,
                                                      const int* __restrict__ ptr,
                                                      const int* __restrict__ perm,
                                                      float* __restrict__ S, int relu_x) {
    int node = blockIdx.x * 4 + (threadIdx.x >> 6);
    int l    = threadIdx.x & 63;
#pragma unroll
    for (int r = 0; r < N_REL; ++r) {
        int b = node * N_REL + r;
        int s = ptr[b], e = ptr[b + 1];
        float2 acc = {0.f, 0.f};
        for (int i = s; i < e; ++i) {
            int src = perm[i];
            float2 v = *reinterpret_cast<const float2*>(X + (size_t)src * 128 + l * 2);
            if (relu_x) { v.x = fmaxf(v.x, 0.f); v.y = fmaxf(v.y, 0.f); }
            acc.x += v.x; acc.y += v.y;
        }
        float sc = 1.0f / (float)max(e - s, 1);
        float2 o = {acc.x * sc, acc.y * sc};
        *reinterpret_cast<float2*>(S + (size_t)node * 512 + (size_t)r * 128 + l * 2) = o;
    }
}

// ================= fused layer GEMM: K = 640 = [x | s0..s3] =================
// C[n,j] = relu_x?(X[n])@Wroot + b + sum_r S[n,r] @ Wrel[r]   (S pre-scaled)
// tile 64 rows x 128 cols (full width), BK=64; micro 4 rows x (4+4) cols.
// All inner-loop ds_read_b128 patterns <=2-way bank aliased (free).

#define ROWF(I, AV)                                                       \
    acc[I][0] = fmaf(AV, bL.x, acc[I][0]); acc[I][1] = fmaf(AV, bL.y, acc[I][1]); \
    acc[I][2] = fmaf(AV, bL.z, acc[I][2]); acc[I][3] = fmaf(AV, bL.w, acc[I][3]); \
    acc[I][4] = fmaf(AV, bH.x, acc[I][4]); acc[I][5] = fmaf(AV, bH.y, acc[I][5]); \
    acc[I][6] = fmaf(AV, bH.z, acc[I][6]); acc[I][7] = fmaf(AV, bH.w, acc[I][7]);

#define LKSTEP(J, AX)                                                          \
    {                                                                          \
        float4 bL = *reinterpret_cast<const float4*>(&Bs[kk + J][tx4]);        \
        float4 bH = *reinterpret_cast<const float4*>(&Bs[kk + J][64 + tx4]);   \
        ROWF(0, aq0.AX) ROWF(1, aq1.AX) ROWF(2, aq2.AX) ROWF(3, aq3.AX)        \
    }

__global__ __launch_bounds__(256, 3) void gemm_layer(const float* __restrict__ X,
                                                     const float* __restrict__ S,
                                                     const float* __restrict__ Wroot,
                                                     const float* __restrict__ Wrel,
                                                     const float* __restrict__ bias,
                                                     float* __restrict__ C, int relu_x) {
    __shared__ __align__(16) float As[64][68];     // 64 rows x 64 k (+pad)
    __shared__ __align__(16) float Bs[64][132];    // 64 k x 128 cols (+pad)
    int t   = threadIdx.x;
    int rm  = blockIdx.x * 64;
    int ty  = t >> 4;          // 0..15 -> rows ty*4..ty*4+3
    int tx4 = (t & 15) * 4;    // cols tx4..tx4+3 and 64+tx4..64+tx4+3
    float acc[4][8];
#pragma unroll
    for (int i = 0; i < 4; ++i)
#pragma unroll
        for (int j = 0; j < 8; ++j) acc[i][j] = 0.f;

    for (int kt = 0; kt < 10; ++kt) {
        // ---- A: 64 rows x 64 k.  k_global = kt*64 + kc ----
#pragma unroll
        for (int i = 0; i < 4; ++i) {
            int idx4 = t + i * 256;
            int row  = idx4 >> 4;          // 0..63
            int kc   = (idx4 & 15) * 4;    // 0..60
            int grow = rm + row;
            float4 v;
            if (kt < 2) {
                v = *reinterpret_cast<const float4*>(X + (size_t)grow * 128 + kt * 64 + kc);
                if (relu_x) {
                    v.x = fmaxf(v.x, 0.f); v.y = fmaxf(v.y, 0.f);
                    v.z = fmaxf(v.z, 0.f); v.w = fmaxf(v.w, 0.f);
                }
            } else {
                v = *reinterpret_cast<const float4*>(
                    S + (size_t)grow * 512 + (kt - 2) * 64 + kc);
            }
            *reinterpret_cast<float4*>(&As[row][kc]) = v;
        }
        // ---- B: 64 k-rows x 128 cols.  [Wroot; Wrel] stacked = [640][128] ----
#pragma unroll
        for (int i = 0; i < 8; ++i) {
            int idx4 = t + i * 256;
            int kk   = idx4 >> 5;          // 0..63
            int j4   = (idx4 & 31) * 4;    // 0..124
            int g    = kt * 64 + kk;       // 0..639
            const float* Bp = (g < 128) ? (Wroot + (size_t)g * 128 + j4)
                                        : (Wrel + (size_t)(g - 128) * 128 + j4);
            *reinterpret_cast<float4*>(&Bs[kk][j4]) = *reinterpret_cast<const float4*>(Bp);
        }
        __syncthreads();
#pragma unroll 2
        for (int kk = 0; kk < 64; kk += 4) {
            float4 aq0 = *reinterpret_cast<const float4*>(&As[ty * 4 + 0][kk]);
            float4 aq1 = *reinterpret_cast<const float4*>(&As[ty * 4 + 1][kk]);
            float4 aq2 = *reinterpret_cast<const float4*>(&As[ty * 4 + 2][kk]);
            float4 aq3 = *reinterpret_cast<const float4*>(&As[ty * 4 + 3][kk]);
            LKSTEP(0, x); LKSTEP(1, y); LKSTEP(2, z); LKSTEP(3, w);
        }
        __syncthreads();
    }
    float4 bvL = *reinterpret_cast<const float4*>(bias + tx4);
    float4 bvH = *reinterpret_cast<const float4*>(bias + 64 + tx4);
#pragma unroll
    for (int i = 0; i < 4; ++i) {
        int grow = rm + ty * 4 + i;
        float4 oL, oH;
        oL.x = acc[i][0] + bvL.x; oL.y = acc[i][1] + bvL.y;
        oL.z = acc[i][2] + bvL.z; oL.w = acc[i][3] + bvL.w;
        oH.x = acc[i][4] + bvH.x; oH.y = acc[i][5] + bvH.y;
        oH.z = acc[i][6] + bvH.z; oH.w = acc[i][7] + bvH.w;
        *reinterpret_cast<float4*>(C + (size_t)grow * 128 + tx4)      = oL;
        *reinterpret_cast<float4*>(C + (size_t)grow * 128 + 64 + tx4) = oH;
    }
}

// ========== head GEMM: gather(nest,food) fused into A-load, relu out ==========
#define FMA16()                                                                 \
    acc[0][0] = fmaf(a0, b.x, acc[0][0]); acc[0][1] = fmaf(a0, b.y, acc[0][1]); \
    acc[0][2] = fmaf(a0, b.z, acc[0][2]); acc[0][3] = fmaf(a0, b.w, acc[0][3]); \
    acc[1][0] = fmaf(a1, b.x, acc[1][0]); acc[1][1] = fmaf(a1, b.y, acc[1][1]); \
    acc[1][2] = fmaf(a1, b.z, acc[1][2]); acc[1][3] = fmaf(a1, b.w, acc[1][3]); \
    acc[2][0] = fmaf(a2, b.x, acc[2][0]); acc[2][1] = fmaf(a2, b.y, acc[2][1]); \
    acc[2][2] = fmaf(a2, b.z, acc[2][2]); acc[2][3] = fmaf(a2, b.w, acc[2][3]); \
    acc[3][0] = fmaf(a3, b.x, acc[3][0]); acc[3][1] = fmaf(a3, b.y, acc[3][1]); \
    acc[3][2] = fmaf(a3, b.z, acc[3][2]); acc[3][3] = fmaf(a3, b.w, acc[3][3])

#define KSTEP(J, AX)                                                \
    {                                                               \
        float4 b  = bq##J;                                          \
        float  a0 = aq0.AX, a1 = aq1.AX, a2 = aq2.AX, a3 = aq3.AX;  \
        FMA16();                                                    \
    }

#define INNER_K128(AS, BS)                                                     \
    _Pragma("unroll 2")                                                        \
    for (int kk = 0; kk < 128; kk += 4) {                                      \
        float4 aq0 = *reinterpret_cast<const float4*>(&AS[ty * 4 + 0][kk]);    \
        float4 aq1 = *reinterpret_cast<const float4*>(&AS[ty * 4 + 1][kk]);    \
        float4 aq2 = *reinterpret_cast<const float4*>(&AS[ty * 4 + 2][kk]);    \
        float4 aq3 = *reinterpret_cast<const float4*>(&AS[ty * 4 + 3][kk]);    \
        float4 bq0 = *reinterpret_cast<const float4*>(&BS[kk + 0][tx * 4]);    \
        float4 bq1 = *reinterpret_cast<const float4*>(&BS[kk + 1][tx * 4]);    \
        float4 bq2 = *reinterpret_cast<const float4*>(&BS[kk + 2][tx * 4]);    \
        float4 bq3 = *reinterpret_cast<const float4*>(&BS[kk + 3][tx * 4]);    \
        KSTEP(0, x); KSTEP(1, y); KSTEP(2, z); KSTEP(3, w);                    \
    }

__global__ __launch_bounds__(256) void gemm_head(const float* __restrict__ H,
                                                 const int* __restrict__ nest,
                                                 const int* __restrict__ food,
                                                 const float* __restrict__ W,
                                                 const float* __restrict__ bias,
                                                 float* __restrict__ C) {
    __shared__ __align__(16) float As[64][132];
    __shared__ __align__(16) float Bs[128][68];
    int t  = threadIdx.x;
    int rm = blockIdx.x * 64;
    int cn = blockIdx.y * 64;
    int ty = t >> 4, tx = t & 15;
    float acc[4][4];
#pragma unroll
    for (int i = 0; i < 4; ++i)
#pragma unroll
        for (int j = 0; j < 4; ++j) acc[i][j] = 0.f;

    for (int kt = 0; kt < 2; ++kt) {
        const int* idx = (kt == 0) ? nest : food;
#pragma unroll
        for (int i = 0; i < 8; ++i) {
            int idx4 = t + i * 256;
            int row  = idx4 >> 5;
            int kc4  = idx4 & 31;
            int node = idx[rm + row];
            *reinterpret_cast<float4*>(&As[row][kc4 * 4]) =
                *reinterpret_cast<const float4*>(H + (size_t)node * 128 + kc4 * 4);
        }
#pragma unroll
        for (int i = 0; i < 8; ++i) {
            int idx4 = t + i * 256;
            int kk   = idx4 >> 4;
            int j4   = idx4 & 15;
            *reinterpret_cast<float4*>(&Bs[kk][j4 * 4]) =
                *reinterpret_cast<const float4*>(W + (size_t)(kt * 128 + kk) * 256 + cn + j4 * 4);
        }
        __syncthreads();
        INNER_K128(As, Bs);
        __syncthreads();
    }
    float4 bv = *reinterpret_cast<const float4*>(bias + cn + tx * 4);
#pragma unroll
    for (int i = 0; i < 4; ++i) {
        int grow = rm + ty * 4 + i;
        float4 o;
        o.x = fmaxf(acc[i][0] + bv.x, 0.f); o.y = fmaxf(acc[i][1] + bv.y, 0.f);
        o.z = fmaxf(acc[i][2] + bv.z, 0.f); o.w = fmaxf(acc[i][3] + bv.w, 0.f);
        *reinterpret_cast<float4*>(C + (size_t)grow * 256 + cn + tx * 4) = o;
    }
}

// ====== heads: logits + log_softmax + dist, one wave per query ======
__global__ __launch_bounds__(256) void head_kernel(const float* __restrict__ hidden,
                                                   const float* __restrict__ dirW,
                                                   const float* __restrict__ dirB,
                                                   const float* __restrict__ distW,
                                                   const float* __restrict__ distB,
                                                   float* __restrict__ outA,
                                                   float* __restrict__ outB) {
    __shared__ __align__(16) float sm[4][256];
    int t = threadIdx.x;
    int w = t >> 6;
    int l = t & 63;
    int q = blockIdx.x * 4 + w;

    float4 hv = *reinterpret_cast<const float4*>(hidden + (size_t)q * 256 + l * 4);
    *reinterpret_cast<float4*>(&sm[w][l * 4]) = hv;
    __syncthreads();

    int v  = l & 15;
    int kc = l >> 4;
    float p = 0.f;
#pragma unroll
    for (int i = 0; i < 64; ++i) {
        int k = kc * 64 + i;
        p = fmaf(sm[w][k], dirW[k * VOCAB + v], p);
    }
    p += __shfl_xor(p, 16);
    p += __shfl_xor(p, 32);
    p += dirB[v];

    float m = p;
#pragma unroll
    for (int d = 1; d < 16; d <<= 1) m = fmaxf(m, __shfl_xor(m, d));
    float es = __expf(p - m);
    float ss = es;
#pragma unroll
    for (int d = 1; d < 16; d <<= 1) ss += __shfl_xor(ss, d);
    float outv = p - m - __logf(ss);
    if (l < 16) outA[(size_t)q * VOCAB + v] = outv;

    float pd = hv.x * distW[l * 4 + 0] + hv.y * distW[l * 4 + 1] +
               hv.z * distW[l * 4 + 2] + hv.w * distW[l * 4 + 3];
#pragma unroll
    for (int d = 1; d < 64; d <<= 1) pd += __shfl_xor(pd, d);
    if (l == 0) outB[q] = pd + distB[0];
}

extern "C" void kernel_launch(void* const* d_in, const int* in_sizes, int n_in,
                              void* d_out, int out_size, void* d_ws, size_t ws_size,
                              hipStream_t stream) {
    const float* x      = (const float*)d_in[0];
    const int*   ei     = (const int*)d_in[1];
    const int*   et     = (const int*)d_in[2];
    const int*   nest   = (const int*)d_in[3];
    const int*   food   = (const int*)d_in[4];
    const float* Wrel1  = (const float*)d_in[5];
    const float* Wroot1 = (const float*)d_in[6];
    const float* b1     = (const float*)d_in[7];
    const float* Wrel2  = (const float*)d_in[8];
    const float* Wroot2 = (const float*)d_in[9];
    const float* b2     = (const float*)d_in[10];
    const float* fcW    = (const float*)d_in[11];
    const float* fcB    = (const float*)d_in[12];
    const float* dirW   = (const float*)d_in[13];
    const float* dirB   = (const float*)d_in[14];
    const float* distW  = (const float*)d_in[15];
    const float* distB  = (const float*)d_in[16];

    char* ws = (char*)d_ws;
    size_t off = 0;
    auto alloc = [&](size_t bytes) {
        void* p = ws + off;
        off += (bytes + 255) & ~(size_t)255;
        return p;
    };
    float* S      = (float*)alloc((size_t)N_NODES * 512 * 4);   // 81.92 MB
    float* hA     = (float*)alloc((size_t)N_NODES * 128 * 4);   // 20.48 MB
    float* hB     = (float*)alloc((size_t)N_NODES * 128 * 4);   // 20.48 MB
    float* hidden = (float*)alloc((size_t)NB * 256 * 4);        //  4.19 MB
    int*   bins   = (int*)alloc((size_t)NBINS * 4);             //  0.64 MB
    int*   ptr    = (int*)alloc((size_t)(NBINS + 1) * 4);
    int*   cur    = (int*)alloc((size_t)(NBINS + 1) * 4);
    int*   bsum   = (int*)alloc(256 * 4);
    int*   boff   = (int*)alloc(256 * 4);
    int*   perm   = (int*)alloc((size_t)N_EDGES * 4);           //  2.56 MB

    float* outA = (float*)d_out;             // [B,16]
    float* outB = (float*)d_out + NB * 16;   // [B]

    const int SCAN_BLKS = (NBINS + 1023) / 1024;   // 157

    // ---- CSR build (shared by both layers) ----
    hipMemsetAsync(bins, 0, (size_t)NBINS * 4, stream);
    hist_kernel<<<(N_EDGES + 255) / 256, 256, 0, stream>>>(ei, et, bins);
    scanA_kernel<<<SCAN_BLKS, 256, 0, stream>>>(bins, ptr, bsum);
    scanB_kernel<<<1, 256, 0, stream>>>(bsum, boff, SCAN_BLKS);
    scanC_kernel<<<SCAN_BLKS, 256, 0, stream>>>(ptr, cur, boff);
    scatter_kernel<<<(N_EDGES + 255) / 256, 256, 0, stream>>>(ei, et, cur, perm);

    // ---- layer 1 ----
    agg_csr_kernel<<<N_NODES / 4, 256, 0, stream>>>(x, ptr, perm, S, 0);
    gemm_layer<<<dim3(625), 256, 0, stream>>>(x, S, Wroot1, Wrel1, b1, hA, 0);

    // ---- layer 2 (inputs relu'd on the fly) ----
    agg_csr_kernel<<<N_NODES / 4, 256, 0, stream>>>(hA, ptr, perm, S, 1);
    gemm_layer<<<dim3(625), 256, 0, stream>>>(hA, S, Wroot2, Wrel2, b2, hB, 1);

    // ---- heads ----
    gemm_head<<<dim3(64, 4), 256, 0, stream>>>(hB, nest, food, fcW, fcB, hidden);
    head_kernel<<<NB / 4, 256, 0, stream>>>(hidden, dirW, dirB, distW, distB, outA, outB);
}

// Round 5
// 418.727 us; speedup vs baseline: 1.3068x; 1.3068x over previous
//
#include <hip/hip_runtime.h>

#define N_NODES 40000
#define N_EDGES 640000
#define N_REL   4
#define NBINS   (N_NODES * N_REL)   // 160000 (dst, rel) segments
#define EMB     128
#define HID     256
#define VOCAB   16
#define NB      4096
#define KTOT    640

typedef __attribute__((ext_vector_type(8))) short bf16x8;
typedef __attribute__((ext_vector_type(4))) float f32x4;

__device__ __forceinline__ short f2bf(float f) {
    union { float f; unsigned u; } x; x.f = f;
    unsigned r = x.u + 0x7fffu + ((x.u >> 16) & 1u);   // RNE to bf16
    return (short)(r >> 16);
}
__device__ __forceinline__ float bf2f(short b) {
    union { unsigned u; float f; } x; x.u = ((unsigned)(unsigned short)b) << 16;
    return x.f;
}

// ================= CSR build: histogram -> scan -> scatter =================

__global__ __launch_bounds__(256) void hist_kernel(const int* __restrict__ ei,
                                                   const int* __restrict__ et,
                                                   int* __restrict__ bins) {
    int e = blockIdx.x * blockDim.x + threadIdx.x;
    if (e < N_EDGES) {
        int dst = ei[N_EDGES + e];
        int r   = et[e];
        atomicAdd(&bins[dst * N_REL + r], 1);
    }
}

__global__ __launch_bounds__(256) void scanA_kernel(const int* __restrict__ bins,
                                                    int* __restrict__ ptr,
                                                    int* __restrict__ bsum) {
    __shared__ int wsum[4];
    int t    = threadIdx.x;
    int base = blockIdx.x * 1024 + t * 4;
    int v[4];
#pragma unroll
    for (int i = 0; i < 4; ++i) {
        int idx = base + i;
        v[i] = (idx < NBINS) ? bins[idx] : 0;
    }
    int tot  = v[0] + v[1] + v[2] + v[3];
    int lane = t & 63, w = t >> 6;
    int inc  = tot;
#pragma unroll
    for (int d = 1; d < 64; d <<= 1) {
        int n = __shfl_up(inc, d);
        if (lane >= d) inc += n;
    }
    if (lane == 63) wsum[w] = inc;
    __syncthreads();
    int woff = 0;
    for (int i = 0; i < w; ++i) woff += wsum[i];
    int run = woff + inc - tot;
#pragma unroll
    for (int i = 0; i < 4; ++i) {
        int idx = base + i;
        if (idx < NBINS) ptr[idx] = run;
        run += v[i];
    }
    if (t == 255) bsum[blockIdx.x] = woff + inc;
}

__global__ __launch_bounds__(256) void scanB_kernel(const int* __restrict__ bsum,
                                                    int* __restrict__ boff, int nblk) {
    __shared__ int sh[256];
    int t = threadIdx.x;
    int v = (t < nblk) ? bsum[t] : 0;
    sh[t] = v;
    __syncthreads();
    for (int d = 1; d < 256; d <<= 1) {
        int n = (t >= d) ? sh[t - d] : 0;
        __syncthreads();
        sh[t] += n;
        __syncthreads();
    }
    if (t < nblk) boff[t] = sh[t] - v;
}

__global__ __launch_bounds__(256) void scanC_kernel(int* __restrict__ ptr,
                                                    int* __restrict__ cur,
                                                    const int* __restrict__ boff) {
    int base = blockIdx.x * 1024 + threadIdx.x * 4;
    int off  = boff[blockIdx.x];
#pragma unroll
    for (int i = 0; i < 4; ++i) {
        int idx = base + i;
        if (idx < NBINS) {
            int p = ptr[idx] + off;
            ptr[idx] = p;
            cur[idx] = p;
        }
    }
    if (blockIdx.x == 0 && threadIdx.x == 0) ptr[NBINS] = N_EDGES;
}

__global__ __launch_bounds__(256) void scatter_kernel(const int* __restrict__ ei,
                                                      const int* __restrict__ et,
                                                      int* __restrict__ cur,
                                                      int* __restrict__ perm) {
    int e = blockIdx.x * blockDim.x + threadIdx.x;
    if (e < N_EDGES) {
        int src = ei[e];
        int dst = ei[N_EDGES + e];
        int r   = et[e];
        int pos = atomicAdd(&cur[dst * N_REL + r], 1);
        perm[pos] = src;
    }
}

// ============ segmented mean-aggregation: S[n,r,:] = mean x[src] ============
__global__ __launch_bounds__(256) void agg_csr_kernel(const float* __restrict__ X,
                                                      const int* __restrict__ ptr,
                                                      const int* __restrict__ perm,
                                                      float* __restrict__ S, int relu_x) {
    int node = blockIdx.x * 4 + (threadIdx.x >> 6);
    int l    = threadIdx.x & 63;
#pragma unroll
    for (int r = 0; r < N_REL; ++r) {
        int b = node * N_REL + r;
        int s = ptr[b], e = ptr[b + 1];
        float2 acc = {0.f, 0.f};
        for (int i = s; i < e; ++i) {
            int src = perm[i];
            float2 v = *reinterpret_cast<const float2*>(X + (size_t)src * 128 + l * 2);
            if (relu_x) { v.x = fmaxf(v.x, 0.f); v.y = fmaxf(v.y, 0.f); }
            acc.x += v.x; acc.y += v.y;
        }
        float sc = 1.0f / (float)max(e - s, 1);
        float2 o = {acc.x * sc, acc.y * sc};
        *reinterpret_cast<float2*>(S + (size_t)node * 512 + (size_t)r * 128 + l * 2) = o;
    }
}

// ============ weight prep: W^T, split into bf16 hi/lo: Wt[col][640] ============
__global__ __launch_bounds__(256) void prep_w(const float* __restrict__ Wroot,
                                              const float* __restrict__ Wrel,
                                              short* __restrict__ Wth,
                                              short* __restrict__ Wtl) {
    int col = blockIdx.x;                       // 0..127
    for (int g = threadIdx.x; g < KTOT; g += 256) {
        float w = (g < 128) ? Wroot[(size_t)g * 128 + col]
                            : Wrel[(size_t)(g - 128) * 128 + col];
        short h  = f2bf(w);
        short lo = f2bf(w - bf2f(h));
        Wth[(size_t)col * KTOT + g] = h;
        Wtl[(size_t)col * KTOT + g] = lo;
    }
}

// ============ fused layer GEMM via split-bf16 MFMA ============
// C[n,j] = relu_x?(X[n])@Wroot + b + sum_r S[n,r] @ Wrel[r]  (S pre-scaled)
// A = [X | S] rows (fp32 -> bf16 hi+lo on stage), B = pre-split W^T bf16.
// Tile 64x128, BK=64, 4 waves in 2m x 2n quadrants; XOR-swizzled LDS.
__global__ __launch_bounds__(256, 3) void gemm_layer_mfma(
        const float* __restrict__ X, const float* __restrict__ S,
        const short* __restrict__ Wth, const short* __restrict__ Wtl,
        const float* __restrict__ bias, float* __restrict__ C, int relu_x) {
    __shared__ __align__(16) short As_h[64 * 64];    //  8 KB
    __shared__ __align__(16) short As_l[64 * 64];    //  8 KB
    __shared__ __align__(16) short Bs_h[128 * 64];   // 16 KB  [col][k]
    __shared__ __align__(16) short Bs_l[128 * 64];   // 16 KB

    const int t   = threadIdx.x;
    const int rm  = blockIdx.x * 64;
    const int l   = t & 63, w = t >> 6;
    const int mh  = (w >> 1) * 32;        // wave row-half
    const int nh  = (w & 1) * 64;         // wave col-half
    const int r16 = l & 15, kch = l >> 4; // MFMA lane coords

    f32x4 acc[2][4];
#pragma unroll
    for (int mt = 0; mt < 2; ++mt)
#pragma unroll
        for (int nt = 0; nt < 4; ++nt)
            acc[mt][nt] = (f32x4){0.f, 0.f, 0.f, 0.f};

    for (int kt = 0; kt < 10; ++kt) {
        // ---- stage A: 64 rows x 64 k, fp32 -> bf16 hi/lo, swizzled ----
#pragma unroll
        for (int i = 0; i < 4; ++i) {
            int idx  = t + i * 256;        // 0..1023
            int row  = idx >> 4;           // 0..63
            int kc   = (idx & 15) * 4;     // 0..60
            int grow = rm + row;
            float4 v;
            if (kt < 2) {
                v = *reinterpret_cast<const float4*>(X + (size_t)grow * 128 + kt * 64 + kc);
                if (relu_x) {
                    v.x = fmaxf(v.x, 0.f); v.y = fmaxf(v.y, 0.f);
                    v.z = fmaxf(v.z, 0.f); v.w = fmaxf(v.w, 0.f);
                }
            } else {
                v = *reinterpret_cast<const float4*>(S + (size_t)grow * 512 + (kt - 2) * 64 + kc);
            }
            short h0 = f2bf(v.x), h1 = f2bf(v.y), h2 = f2bf(v.z), h3 = f2bf(v.w);
            short l0 = f2bf(v.x - bf2f(h0)), l1 = f2bf(v.y - bf2f(h1));
            short l2 = f2bf(v.z - bf2f(h2)), l3 = f2bf(v.w - bf2f(h3));
            int off = ((row << 7) + (kc << 1)) ^ ((row & 7) << 4);
            *reinterpret_cast<short4*>((char*)As_h + off) = make_short4(h0, h1, h2, h3);
            *reinterpret_cast<short4*>((char*)As_l + off) = make_short4(l0, l1, l2, l3);
        }
        // ---- stage B: 128 cols x 64 k from pre-split W^T, swizzled ----
#pragma unroll
        for (int i = 0; i < 4; ++i) {
            int idx = t + i * 256;         // 0..1023
            int col = idx >> 3;            // 0..127
            int k0  = (idx & 7) * 8;       // 0..56
            size_t goff = (size_t)col * KTOT + kt * 64 + k0;
            bf16x8 hv = *reinterpret_cast<const bf16x8*>(Wth + goff);
            bf16x8 lv = *reinterpret_cast<const bf16x8*>(Wtl + goff);
            int off = ((col << 7) + (k0 << 1)) ^ ((col & 7) << 4);
            *reinterpret_cast<bf16x8*>((char*)Bs_h + off) = hv;
            *reinterpret_cast<bf16x8*>((char*)Bs_l + off) = lv;
        }
        __syncthreads();
        // ---- 2 x K32 MFMA steps ----
#pragma unroll
        for (int s = 0; s < 2; ++s) {
            int kb = s * 64 + kch * 16;    // byte offset of this lane's k-chunk
            bf16x8 ah[2], al[2], bh[4], bl[4];
#pragma unroll
            for (int mt = 0; mt < 2; ++mt) {
                int row = mh + mt * 16 + r16;
                int off = ((row << 7) + kb) ^ ((row & 7) << 4);
                ah[mt] = *reinterpret_cast<const bf16x8*>((const char*)As_h + off);
                al[mt] = *reinterpret_cast<const bf16x8*>((const char*)As_l + off);
            }
#pragma unroll
            for (int nt = 0; nt < 4; ++nt) {
                int col = nh + nt * 16 + r16;
                int off = ((col << 7) + kb) ^ ((col & 7) << 4);
                bh[nt] = *reinterpret_cast<const bf16x8*>((const char*)Bs_h + off);
                bl[nt] = *reinterpret_cast<const bf16x8*>((const char*)Bs_l + off);
            }
#pragma unroll
            for (int mt = 0; mt < 2; ++mt)
#pragma unroll
                for (int nt = 0; nt < 4; ++nt) {
                    acc[mt][nt] = __builtin_amdgcn_mfma_f32_16x16x32_bf16(ah[mt], bh[nt], acc[mt][nt], 0, 0, 0);
                    acc[mt][nt] = __builtin_amdgcn_mfma_f32_16x16x32_bf16(ah[mt], bl[nt], acc[mt][nt], 0, 0, 0);
                    acc[mt][nt] = __builtin_amdgcn_mfma_f32_16x16x32_bf16(al[mt], bh[nt], acc[mt][nt], 0, 0, 0);
                }
        }
        __syncthreads();
    }
    // ---- epilogue: C/D layout col=l&15, row=(l>>4)*4+r ----
#pragma unroll
    for (int mt = 0; mt < 2; ++mt)
#pragma unroll
        for (int nt = 0; nt < 4; ++nt) {
            int col = nh + nt * 16 + r16;
            float bv = bias[col];
#pragma unroll
            for (int r = 0; r < 4; ++r) {
                int row = rm + mh + mt * 16 + kch * 4 + r;
                C[(size_t)row * 128 + col] = acc[mt][nt][r] + bv;
            }
        }
}

// ========== head GEMM (fp32): gather(nest,food) fused, relu out ==========
#define FMA16()                                                                 \
    acc[0][0] = fmaf(a0, b.x, acc[0][0]); acc[0][1] = fmaf(a0, b.y, acc[0][1]); \
    acc[0][2] = fmaf(a0, b.z, acc[0][2]); acc[0][3] = fmaf(a0, b.w, acc[0][3]); \
    acc[1][0] = fmaf(a1, b.x, acc[1][0]); acc[1][1] = fmaf(a1, b.y, acc[1][1]); \
    acc[1][2] = fmaf(a1, b.z, acc[1][2]); acc[1][3] = fmaf(a1, b.w, acc[1][3]); \
    acc[2][0] = fmaf(a2, b.x, acc[2][0]); acc[2][1] = fmaf(a2, b.y, acc[2][1]); \
    acc[2][2] = fmaf(a2, b.z, acc[2][2]); acc[2][3] = fmaf(a2, b.w, acc[2][3]); \
    acc[3][0] = fmaf(a3, b.x, acc[3][0]); acc[3][1] = fmaf(a3, b.y, acc[3][1]); \
    acc[3][2] = fmaf(a3, b.z, acc[3][2]); acc[3][3] = fmaf(a3, b.w, acc[3][3])

#define KSTEP(J, AX)                                                \
    {                                                               \
        float4 b  = bq##J;                                          \
        float  a0 = aq0.AX, a1 = aq1.AX, a2 = aq2.AX, a3 = aq3.AX;  \
        FMA16();                                                    \
    }

#define INNER_K128(AS, BS)                                                     \
    _Pragma("unroll 2")                                                        \
    for (int kk = 0; kk < 128; kk += 4) {                                      \
        float4 aq0 = *reinterpret_cast<const float4*>(&AS[ty * 4 + 0][kk]);    \
        float4 aq1 = *reinterpret_cast<const float4*>(&AS[ty * 4 + 1][kk]);    \
        float4 aq2 = *reinterpret_cast<const float4*>(&AS[ty * 4 + 2][kk]);    \
        float4 aq3 = *reinterpret_cast<const float4*>(&AS[ty * 4 + 3][kk]);    \
        float4 bq0 = *reinterpret_cast<const float4*>(&BS[kk + 0][tx * 4]);    \
        float4 bq1 = *reinterpret_cast<const float4*>(&BS[kk + 1][tx * 4]);    \
        float4 bq2 = *reinterpret_cast<const float4*>(&BS[kk + 2][tx * 4]);    \
        float4 bq3 = *reinterpret_cast<const float4*>(&BS[kk + 3][tx * 4]);    \
        KSTEP(0, x); KSTEP(1, y); KSTEP(2, z); KSTEP(3, w);                    \
    }

__global__ __launch_bounds__(256) void gemm_head(const float* __restrict__ H,
                                                 const int* __restrict__ nest,
                                                 const int* __restrict__ food,
                                                 const float* __restrict__ W,
                                                 const float* __restrict__ bias,
                                                 float* __restrict__ C) {
    __shared__ __align__(16) float As[64][132];
    __shared__ __align__(16) float Bs[128][68];
    int t  = threadIdx.x;
    int rm = blockIdx.x * 64;
    int cn = blockIdx.y * 64;
    int ty = t >> 4, tx = t & 15;
    float acc[4][4];
#pragma unroll
    for (int i = 0; i < 4; ++i)
#pragma unroll
        for (int j = 0; j < 4; ++j) acc[i][j] = 0.f;

    for (int kt = 0; kt < 2; ++kt) {
        const int* idx = (kt == 0) ? nest : food;
#pragma unroll
        for (int i = 0; i < 8; ++i) {
            int idx4 = t + i * 256;
            int row  = idx4 >> 5;
            int kc4  = idx4 & 31;
            int node = idx[rm + row];
            *reinterpret_cast<float4*>(&As[row][kc4 * 4]) =
                *reinterpret_cast<const float4*>(H + (size_t)node * 128 + kc4 * 4);
        }
#pragma unroll
        for (int i = 0; i < 8; ++i) {
            int idx4 = t + i * 256;
            int kk   = idx4 >> 4;
            int j4   = idx4 & 15;
            *reinterpret_cast<float4*>(&Bs[kk][j4 * 4]) =
                *reinterpret_cast<const float4*>(W + (size_t)(kt * 128 + kk) * 256 + cn + j4 * 4);
        }
        __syncthreads();
        INNER_K128(As, Bs);
        __syncthreads();
    }
    float4 bv = *reinterpret_cast<const float4*>(bias + cn + tx * 4);
#pragma unroll
    for (int i = 0; i < 4; ++i) {
        int grow = rm + ty * 4 + i;
        float4 o;
        o.x = fmaxf(acc[i][0] + bv.x, 0.f); o.y = fmaxf(acc[i][1] + bv.y, 0.f);
        o.z = fmaxf(acc[i][2] + bv.z, 0.f); o.w = fmaxf(acc[i][3] + bv.w, 0.f);
        *reinterpret_cast<float4*>(C + (size_t)grow * 256 + cn + tx * 4) = o;
    }
}

// ====== heads: logits + log_softmax + dist, one wave per query ======
__global__ __launch_bounds__(256) void head_kernel(const float* __restrict__ hidden,
                                                   const float* __restrict__ dirW,
                                                   const float* __restrict__ dirB,
                                                   const float* __restrict__ distW,
                                                   const float* __restrict__ distB,
                                                   float* __restrict__ outA,
                                                   float* __restrict__ outB) {
    __shared__ __align__(16) float sm[4][256];
    int t = threadIdx.x;
    int w = t >> 6;
    int l = t & 63;
    int q = blockIdx.x * 4 + w;

    float4 hv = *reinterpret_cast<const float4*>(hidden + (size_t)q * 256 + l * 4);
    *reinterpret_cast<float4*>(&sm[w][l * 4]) = hv;
    __syncthreads();

    int v  = l & 15;
    int kc = l >> 4;
    float p = 0.f;
#pragma unroll
    for (int i = 0; i < 64; ++i) {
        int k = kc * 64 + i;
        p = fmaf(sm[w][k], dirW[k * VOCAB + v], p);
    }
    p += __shfl_xor(p, 16);
    p += __shfl_xor(p, 32);
    p += dirB[v];

    float m = p;
#pragma unroll
    for (int d = 1; d < 16; d <<= 1) m = fmaxf(m, __shfl_xor(m, d));
    float es = __expf(p - m);
    float ss = es;
#pragma unroll
    for (int d = 1; d < 16; d <<= 1) ss += __shfl_xor(ss, d);
    float outv = p - m - __logf(ss);
    if (l < 16) outA[(size_t)q * VOCAB + v] = outv;

    float pd = hv.x * distW[l * 4 + 0] + hv.y * distW[l * 4 + 1] +
               hv.z * distW[l * 4 + 2] + hv.w * distW[l * 4 + 3];
#pragma unroll
    for (int d = 1; d < 64; d <<= 1) pd += __shfl_xor(pd, d);
    if (l == 0) outB[q] = pd + distB[0];
}

extern "C" void kernel_launch(void* const* d_in, const int* in_sizes, int n_in,
                              void* d_out, int out_size, void* d_ws, size_t ws_size,
                              hipStream_t stream) {
    const float* x      = (const float*)d_in[0];
    const int*   ei     = (const int*)d_in[1];
    const int*   et     = (const int*)d_in[2];
    const int*   nest   = (const int*)d_in[3];
    const int*   food   = (const int*)d_in[4];
    const float* Wrel1  = (const float*)d_in[5];
    const float* Wroot1 = (const float*)d_in[6];
    const float* b1     = (const float*)d_in[7];
    const float* Wrel2  = (const float*)d_in[8];
    const float* Wroot2 = (const float*)d_in[9];
    const float* b2     = (const float*)d_in[10];
    const float* fcW    = (const float*)d_in[11];
    const float* fcB    = (const float*)d_in[12];
    const float* dirW   = (const float*)d_in[13];
    const float* dirB   = (const float*)d_in[14];
    const float* distW  = (const float*)d_in[15];
    const float* distB  = (const float*)d_in[16];

    char* ws = (char*)d_ws;
    size_t off = 0;
    auto alloc = [&](size_t bytes) {
        void* p = ws + off;
        off += (bytes + 255) & ~(size_t)255;
        return p;
    };
    float* S      = (float*)alloc((size_t)N_NODES * 512 * 4);   // 81.92 MB
    float* hA     = (float*)alloc((size_t)N_NODES * 128 * 4);   // 20.48 MB
    float* hB     = (float*)alloc((size_t)N_NODES * 128 * 4);   // 20.48 MB
    float* hidden = (float*)alloc((size_t)NB * 256 * 4);        //  4.19 MB
    // wtbuf aliases the bins histogram (bins dead after scanA; prep_w runs after scatter)
    short* wtbuf  = (short*)alloc((size_t)4 * 128 * KTOT * 2);  // 0.655 MB
    int*   bins   = (int*)wtbuf;                                // needs 0.64 MB
    int*   ptr    = (int*)alloc((size_t)(NBINS + 1) * 4);
    int*   cur    = (int*)alloc((size_t)(NBINS + 1) * 4);
    int*   bsum   = (int*)alloc(256 * 4);
    int*   boff   = (int*)alloc(256 * 4);
    int*   perm   = (int*)alloc((size_t)N_EDGES * 4);           //  2.56 MB

    short* wt1h = wtbuf;
    short* wt1l = wtbuf + 128 * KTOT;
    short* wt2h = wtbuf + 2 * 128 * KTOT;
    short* wt2l = wtbuf + 3 * 128 * KTOT;

    float* outA = (float*)d_out;             // [B,16]
    float* outB = (float*)d_out + NB * 16;   // [B]

    const int SCAN_BLKS = (NBINS + 1023) / 1024;   // 157

    // ---- CSR build (shared by both layers; uses bins region first) ----
    hipMemsetAsync(bins, 0, (size_t)NBINS * 4, stream);
    hist_kernel<<<(N_EDGES + 255) / 256, 256, 0, stream>>>(ei, et, bins);
    scanA_kernel<<<SCAN_BLKS, 256, 0, stream>>>(bins, ptr, bsum);
    scanB_kernel<<<1, 256, 0, stream>>>(bsum, boff, SCAN_BLKS);
    scanC_kernel<<<SCAN_BLKS, 256, 0, stream>>>(ptr, cur, boff);
    scatter_kernel<<<(N_EDGES + 255) / 256, 256, 0, stream>>>(ei, et, cur, perm);

    // ---- weight prep (overwrites dead bins region) ----
    prep_w<<<128, 256, 0, stream>>>(Wroot1, Wrel1, wt1h, wt1l);
    prep_w<<<128, 256, 0, stream>>>(Wroot2, Wrel2, wt2h, wt2l);

    // ---- layer 1 ----
    agg_csr_kernel<<<N_NODES / 4, 256, 0, stream>>>(x, ptr, perm, S, 0);
    gemm_layer_mfma<<<625, 256, 0, stream>>>(x, S, wt1h, wt1l, b1, hA, 0);

    // ---- layer 2 (inputs relu'd on the fly) ----
    agg_csr_kernel<<<N_NODES / 4, 256, 0, stream>>>(hA, ptr, perm, S, 1);
    gemm_layer_mfma<<<625, 256, 0, stream>>>(hA, S, wt2h, wt2l, b2, hB, 1);

    // ---- heads ----
    gemm_head<<<dim3(64, 4), 256, 0, stream>>>(hB, nest, food, fcW, fcB, hidden);
    head_kernel<<<NB / 4, 256, 0, stream>>>(hidden, dirW, dirB, distW, distB, outA, outB);
}

// Round 7
// 369.233 us; speedup vs baseline: 1.4820x; 1.1340x over previous
//
#include <hip/hip_runtime.h>

#define N_NODES 40000
#define N_EDGES 640000
#define N_REL   4
#define NBINS   (N_NODES * N_REL)   // 160000 (dst, rel) segments
#define EMB     128
#define HID     256
#define VOCAB   16
#define NB      4096
#define KTOT    640

typedef __attribute__((ext_vector_type(8))) short bf16x8;
typedef __attribute__((ext_vector_type(4))) float f32x4;

__device__ __forceinline__ short f2bf(float f) {
    union { float f; unsigned u; } x; x.f = f;
    unsigned r = x.u + 0x7fffu + ((x.u >> 16) & 1u);   // RNE to bf16
    return (short)(r >> 16);
}
__device__ __forceinline__ float bf2f(short b) {
    union { unsigned u; float f; } x; x.u = ((unsigned)(unsigned short)b) << 16;
    return x.f;
}

// ================= CSR build: histogram -> scan -> scatter =================

__global__ __launch_bounds__(256) void hist_kernel(const int* __restrict__ ei,
                                                   const int* __restrict__ et,
                                                   int* __restrict__ bins) {
    int e = blockIdx.x * blockDim.x + threadIdx.x;
    if (e < N_EDGES) {
        int dst = ei[N_EDGES + e];
        int r   = et[e];
        atomicAdd(&bins[dst * N_REL + r], 1);
    }
}

__global__ __launch_bounds__(256) void scanA_kernel(const int* __restrict__ bins,
                                                    int* __restrict__ ptr,
                                                    int* __restrict__ bsum) {
    __shared__ int wsum[4];
    int t    = threadIdx.x;
    int base = blockIdx.x * 1024 + t * 4;
    int v[4];
#pragma unroll
    for (int i = 0; i < 4; ++i) {
        int idx = base + i;
        v[i] = (idx < NBINS) ? bins[idx] : 0;
    }
    int tot  = v[0] + v[1] + v[2] + v[3];
    int lane = t & 63, w = t >> 6;
    int inc  = tot;
#pragma unroll
    for (int d = 1; d < 64; d <<= 1) {
        int n = __shfl_up(inc, d);
        if (lane >= d) inc += n;
    }
    if (lane == 63) wsum[w] = inc;
    __syncthreads();
    int woff = 0;
    for (int i = 0; i < w; ++i) woff += wsum[i];
    int run = woff + inc - tot;
#pragma unroll
    for (int i = 0; i < 4; ++i) {
        int idx = base + i;
        if (idx < NBINS) ptr[idx] = run;
        run += v[i];
    }
    if (t == 255) bsum[blockIdx.x] = woff + inc;
}

__global__ __launch_bounds__(256) void scanB_kernel(const int* __restrict__ bsum,
                                                    int* __restrict__ boff, int nblk) {
    __shared__ int sh[256];
    int t = threadIdx.x;
    int v = (t < nblk) ? bsum[t] : 0;
    sh[t] = v;
    __syncthreads();
    for (int d = 1; d < 256; d <<= 1) {
        int n = (t >= d) ? sh[t - d] : 0;
        __syncthreads();
        sh[t] += n;
        __syncthreads();
    }
    if (t < nblk) boff[t] = sh[t] - v;
}

__global__ __launch_bounds__(256) void scanC_kernel(int* __restrict__ ptr,
                                                    int* __restrict__ cur,
                                                    const int* __restrict__ boff) {
    int base = blockIdx.x * 1024 + threadIdx.x * 4;
    int off  = boff[blockIdx.x];
#pragma unroll
    for (int i = 0; i < 4; ++i) {
        int idx = base + i;
        if (idx < NBINS) {
            int p = ptr[idx] + off;
            ptr[idx] = p;
            cur[idx] = p;
        }
    }
    if (blockIdx.x == 0 && threadIdx.x == 0) ptr[NBINS] = N_EDGES;
}

__global__ __launch_bounds__(256) void scatter_kernel(const int* __restrict__ ei,
                                                      const int* __restrict__ et,
                                                      int* __restrict__ cur,
                                                      int* __restrict__ perm) {
    int e = blockIdx.x * blockDim.x + threadIdx.x;
    if (e < N_EDGES) {
        int src = ei[e];
        int dst = ei[N_EDGES + e];
        int r   = et[e];
        int pos = atomicAdd(&cur[dst * N_REL + r], 1);
        perm[pos] = src;
    }
}

// ============ segmented mean-aggregation: S[n,r,:] = mean x[src] ============
// One wave per node. A node's 4 relation segments are CONTIGUOUS in perm
// [ptr[n*4], ptr[n*4+4]), so one 64-lane vector load grabs all edge srcs;
// edges are then broadcast via shfl and their X-rows loaded with 4-deep ILP.
// Relation routing by index-vs-boundary compares into 4 register accumulators.
__global__ __launch_bounds__(256) void agg_csr_kernel(const float* __restrict__ X,
                                                      const int* __restrict__ ptr,
                                                      const int* __restrict__ perm,
                                                      float* __restrict__ S, int relu_x) {
    int node = blockIdx.x * 4 + (threadIdx.x >> 6);
    int l    = threadIdx.x & 63;

    int base = ptr[node * 4 + 0];
    int b1   = ptr[node * 4 + 1];
    int b2   = ptr[node * 4 + 2];
    int b3   = ptr[node * 4 + 3];
    int end  = ptr[node * 4 + 4];

    float2 a0 = {0.f, 0.f}, a1 = {0.f, 0.f}, a2 = {0.f, 0.f}, a3 = {0.f, 0.f};

    for (int cbase = base; cbase < end; cbase += 64) {
        int cnt  = min(64, end - cbase);
        int srcs = (l < cnt) ? perm[cbase + l] : 0;   // all edges of chunk, one load
        for (int j = 0; j < cnt; j += 4) {
            float2 v[4]; int rsel[4]; bool val[4];
#pragma unroll
            for (int u = 0; u < 4; ++u) {
                int jj  = j + u;
                val[u]  = jj < cnt;
                int src = __shfl(srcs, val[u] ? jj : 0);
                int gi  = cbase + jj;
                rsel[u] = (gi >= b1) + (gi >= b2) + (gi >= b3);
                v[u] = *reinterpret_cast<const float2*>(X + (size_t)src * 128 + l * 2);
            }
#pragma unroll
            for (int u = 0; u < 4; ++u) {
                float2 w = v[u];
                if (relu_x) { w.x = fmaxf(w.x, 0.f); w.y = fmaxf(w.y, 0.f); }
                float m0 = (val[u] && rsel[u] == 0) ? 1.f : 0.f;
                float m1 = (val[u] && rsel[u] == 1) ? 1.f : 0.f;
                float m2 = (val[u] && rsel[u] == 2) ? 1.f : 0.f;
                float m3 = (val[u] && rsel[u] == 3) ? 1.f : 0.f;
                a0.x = fmaf(w.x, m0, a0.x); a0.y = fmaf(w.y, m0, a0.y);
                a1.x = fmaf(w.x, m1, a1.x); a1.y = fmaf(w.y, m1, a1.y);
                a2.x = fmaf(w.x, m2, a2.x); a2.y = fmaf(w.y, m2, a2.y);
                a3.x = fmaf(w.x, m3, a3.x); a3.y = fmaf(w.y, m3, a3.y);
            }
        }
    }

    float s0 = 1.0f / (float)max(b1 - base, 1);
    float s1 = 1.0f / (float)max(b2 - b1, 1);
    float s2 = 1.0f / (float)max(b3 - b2, 1);
    float s3 = 1.0f / (float)max(end - b3, 1);
    float* Sp = S + (size_t)node * 512 + l * 2;
    *reinterpret_cast<float2*>(Sp + 0 * 128) = make_float2(a0.x * s0, a0.y * s0);
    *reinterpret_cast<float2*>(Sp + 1 * 128) = make_float2(a1.x * s1, a1.y * s1);
    *reinterpret_cast<float2*>(Sp + 2 * 128) = make_float2(a2.x * s2, a2.y * s2);
    *reinterpret_cast<float2*>(Sp + 3 * 128) = make_float2(a3.x * s3, a3.y * s3);
}

// ============ weight prep: W^T, split into bf16 hi/lo: Wt[col][640] ============
__global__ __launch_bounds__(256) void prep_w(const float* __restrict__ Wroot,
                                              const float* __restrict__ Wrel,
                                              short* __restrict__ Wth,
                                              short* __restrict__ Wtl) {
    int col = blockIdx.x;                       // 0..127
    for (int g = threadIdx.x; g < KTOT; g += 256) {
        float w = (g < 128) ? Wroot[(size_t)g * 128 + col]
                            : Wrel[(size_t)(g - 128) * 128 + col];
        short h  = f2bf(w);
        short lo = f2bf(w - bf2f(h));
        Wth[(size_t)col * KTOT + g] = h;
        Wtl[(size_t)col * KTOT + g] = lo;
    }
}

// ============ fused layer GEMM via split-bf16 MFMA ============
__global__ __launch_bounds__(256, 3) void gemm_layer_mfma(
        const float* __restrict__ X, const float* __restrict__ S,
        const short* __restrict__ Wth, const short* __restrict__ Wtl,
        const float* __restrict__ bias, float* __restrict__ C, int relu_x) {
    __shared__ __align__(16) short As_h[64 * 64];    //  8 KB
    __shared__ __align__(16) short As_l[64 * 64];    //  8 KB
    __shared__ __align__(16) short Bs_h[128 * 64];   // 16 KB  [col][k]
    __shared__ __align__(16) short Bs_l[128 * 64];   // 16 KB

    const int t   = threadIdx.x;
    const int rm  = blockIdx.x * 64;
    const int l   = t & 63, w = t >> 6;
    const int mh  = (w >> 1) * 32;        // wave row-half
    const int nh  = (w & 1) * 64;         // wave col-half
    const int r16 = l & 15, kch = l >> 4; // MFMA lane coords

    f32x4 acc[2][4];
#pragma unroll
    for (int mt = 0; mt < 2; ++mt)
#pragma unroll
        for (int nt = 0; nt < 4; ++nt)
            acc[mt][nt] = (f32x4){0.f, 0.f, 0.f, 0.f};

    for (int kt = 0; kt < 10; ++kt) {
        // ---- stage A: 64 rows x 64 k, fp32 -> bf16 hi/lo, swizzled ----
#pragma unroll
        for (int i = 0; i < 4; ++i) {
            int idx  = t + i * 256;        // 0..1023
            int row  = idx >> 4;           // 0..63
            int kc   = (idx & 15) * 4;     // 0..60
            int grow = rm + row;
            float4 v;
            if (kt < 2) {
                v = *reinterpret_cast<const float4*>(X + (size_t)grow * 128 + kt * 64 + kc);
                if (relu_x) {
                    v.x = fmaxf(v.x, 0.f); v.y = fmaxf(v.y, 0.f);
                    v.z = fmaxf(v.z, 0.f); v.w = fmaxf(v.w, 0.f);
                }
            } else {
                v = *reinterpret_cast<const float4*>(S + (size_t)grow * 512 + (kt - 2) * 64 + kc);
            }
            short h0 = f2bf(v.x), h1 = f2bf(v.y), h2 = f2bf(v.z), h3 = f2bf(v.w);
            short l0 = f2bf(v.x - bf2f(h0)), l1 = f2bf(v.y - bf2f(h1));
            short l2 = f2bf(v.z - bf2f(h2)), l3 = f2bf(v.w - bf2f(h3));
            int off = ((row << 7) + (kc << 1)) ^ ((row & 7) << 4);
            *reinterpret_cast<short4*>((char*)As_h + off) = make_short4(h0, h1, h2, h3);
            *reinterpret_cast<short4*>((char*)As_l + off) = make_short4(l0, l1, l2, l3);
        }
        // ---- stage B: 128 cols x 64 k from pre-split W^T, swizzled ----
#pragma unroll
        for (int i = 0; i < 4; ++i) {
            int idx = t + i * 256;         // 0..1023
            int col = idx >> 3;            // 0..127
            int k0  = (idx & 7) * 8;       // 0..56
            size_t goff = (size_t)col * KTOT + kt * 64 + k0;
            bf16x8 hv = *reinterpret_cast<const bf16x8*>(Wth + goff);
            bf16x8 lv = *reinterpret_cast<const bf16x8*>(Wtl + goff);
            int off = ((col << 7) + (k0 << 1)) ^ ((col & 7) << 4);
            *reinterpret_cast<bf16x8*>((char*)Bs_h + off) = hv;
            *reinterpret_cast<bf16x8*>((char*)Bs_l + off) = lv;
        }
        __syncthreads();
        // ---- 2 x K32 MFMA steps ----
#pragma unroll
        for (int s = 0; s < 2; ++s) {
            int kb = s * 64 + kch * 16;    // byte offset of this lane's k-chunk
            bf16x8 ah[2], al[2], bh[4], bl[4];
#pragma unroll
            for (int mt = 0; mt < 2; ++mt) {
                int row = mh + mt * 16 + r16;
                int off = ((row << 7) + kb) ^ ((row & 7) << 4);
                ah[mt] = *reinterpret_cast<const bf16x8*>((const char*)As_h + off);
                al[mt] = *reinterpret_cast<const bf16x8*>((const char*)As_l + off);
            }
#pragma unroll
            for (int nt = 0; nt < 4; ++nt) {
                int col = nh + nt * 16 + r16;
                int off = ((col << 7) + kb) ^ ((col & 7) << 4);
                bh[nt] = *reinterpret_cast<const bf16x8*>((const char*)Bs_h + off);
                bl[nt] = *reinterpret_cast<const bf16x8*>((const char*)Bs_l + off);
            }
#pragma unroll
            for (int mt = 0; mt < 2; ++mt)
#pragma unroll
                for (int nt = 0; nt < 4; ++nt) {
                    acc[mt][nt] = __builtin_amdgcn_mfma_f32_16x16x32_bf16(ah[mt], bh[nt], acc[mt][nt], 0, 0, 0);
                    acc[mt][nt] = __builtin_amdgcn_mfma_f32_16x16x32_bf16(ah[mt], bl[nt], acc[mt][nt], 0, 0, 0);
                    acc[mt][nt] = __builtin_amdgcn_mfma_f32_16x16x32_bf16(al[mt], bh[nt], acc[mt][nt], 0, 0, 0);
                }
        }
        __syncthreads();
    }
    // ---- epilogue: C/D layout col=l&15, row=(l>>4)*4+r ----
#pragma unroll
    for (int mt = 0; mt < 2; ++mt)
#pragma unroll
        for (int nt = 0; nt < 4; ++nt) {
            int col = nh + nt * 16 + r16;
            float bv = bias[col];
#pragma unroll
            for (int r = 0; r < 4; ++r) {
                int row = rm + mh + mt * 16 + kch * 4 + r;
                C[(size_t)row * 128 + col] = acc[mt][nt][r] + bv;
            }
        }
}

// ========== head GEMM (fp32): gather(nest,food) fused, relu out ==========
#define FMA16()                                                                 \
    acc[0][0] = fmaf(a0, b.x, acc[0][0]); acc[0][1] = fmaf(a0, b.y, acc[0][1]); \
    acc[0][2] = fmaf(a0, b.z, acc[0][2]); acc[0][3] = fmaf(a0, b.w, acc[0][3]); \
    acc[1][0] = fmaf(a1, b.x, acc[1][0]); acc[1][1] = fmaf(a1, b.y, acc[1][1]); \
    acc[1][2] = fmaf(a1, b.z, acc[1][2]); acc[1][3] = fmaf(a1, b.w, acc[1][3]); \
    acc[2][0] = fmaf(a2, b.x, acc[2][0]); acc[2][1] = fmaf(a2, b.y, acc[2][1]); \
    acc[2][2] = fmaf(a2, b.z, acc[2][2]); acc[2][3] = fmaf(a2, b.w, acc[2][3]); \
    acc[3][0] = fmaf(a3, b.x, acc[3][0]); acc[3][1] = fmaf(a3, b.y, acc[3][1]); \
    acc[3][2] = fmaf(a3, b.z, acc[3][2]); acc[3][3] = fmaf(a3, b.w, acc[3][3])

#define KSTEP(J, AX)                                                \
    {                                                               \
        float4 b  = bq##J;                                          \
        float  a0 = aq0.AX, a1 = aq1.AX, a2 = aq2.AX, a3 = aq3.AX;  \
        FMA16();                                                    \
    }

#define INNER_K128(AS, BS)                                                     \
    _Pragma("unroll 2")                                                        \
    for (int kk = 0; kk < 128; kk += 4) {                                      \
        float4 aq0 = *reinterpret_cast<const float4*>(&AS[ty * 4 + 0][kk]);    \
        float4 aq1 = *reinterpret_cast<const float4*>(&AS[ty * 4 + 1][kk]);    \
        float4 aq2 = *reinterpret_cast<const float4*>(&AS[ty * 4 + 2][kk]);    \
        float4 aq3 = *reinterpret_cast<const float4*>(&AS[ty * 4 + 3][kk]);    \
        float4 bq0 = *reinterpret_cast<const float4*>(&BS[kk + 0][tx * 4]);    \
        float4 bq1 = *reinterpret_cast<const float4*>(&BS[kk + 1][tx * 4]);    \
        float4 bq2 = *reinterpret_cast<const float4*>(&BS[kk + 2][tx * 4]);    \
        float4 bq3 = *reinterpret_cast<const float4*>(&BS[kk + 3][tx * 4]);    \
        KSTEP(0, x); KSTEP(1, y); KSTEP(2, z); KSTEP(3, w);                    \
    }

__global__ __launch_bounds__(256) void gemm_head(const float* __restrict__ H,
                                                 const int* __restrict__ nest,
                                                 const int* __restrict__ food,
                                                 const float* __restrict__ W,
                                                 const float* __restrict__ bias,
                                                 float* __restrict__ C) {
    __shared__ __align__(16) float As[64][132];
    __shared__ __align__(16) float Bs[128][68];
    int t  = threadIdx.x;
    int rm = blockIdx.x * 64;
    int cn = blockIdx.y * 64;
    int ty = t >> 4, tx = t & 15;
    float acc[4][4];
#pragma unroll
    for (int i = 0; i < 4; ++i)
#pragma unroll
        for (int j = 0; j < 4; ++j) acc[i][j] = 0.f;

    for (int kt = 0; kt < 2; ++kt) {
        const int* idx = (kt == 0) ? nest : food;
#pragma unroll
        for (int i = 0; i < 8; ++i) {
            int idx4 = t + i * 256;
            int row  = idx4 >> 5;
            int kc4  = idx4 & 31;
            int node = idx[rm + row];
            *reinterpret_cast<float4*>(&As[row][kc4 * 4]) =
                *reinterpret_cast<const float4*>(H + (size_t)node * 128 + kc4 * 4);
        }
#pragma unroll
        for (int i = 0; i < 8; ++i) {
            int idx4 = t + i * 256;
            int kk   = idx4 >> 4;
            int j4   = idx4 & 15;
            *reinterpret_cast<float4*>(&Bs[kk][j4 * 4]) =
                *reinterpret_cast<const float4*>(W + (size_t)(kt * 128 + kk) * 256 + cn + j4 * 4);
        }
        __syncthreads();
        INNER_K128(As, Bs);
        __syncthreads();
    }
    float4 bv = *reinterpret_cast<const float4*>(bias + cn + tx * 4);
#pragma unroll
    for (int i = 0; i < 4; ++i) {
        int grow = rm + ty * 4 + i;
        float4 o;
        o.x = fmaxf(acc[i][0] + bv.x, 0.f); o.y = fmaxf(acc[i][1] + bv.y, 0.f);
        o.z = fmaxf(acc[i][2] + bv.z, 0.f); o.w = fmaxf(acc[i][3] + bv.w, 0.f);
        *reinterpret_cast<float4*>(C + (size_t)grow * 256 + cn + tx * 4) = o;
    }
}

// ====== heads: logits + log_softmax + dist, one wave per query ======
__global__ __launch_bounds__(256) void head_kernel(const float* __restrict__ hidden,
                                                   const float* __restrict__ dirW,
                                                   const float* __restrict__ dirB,
                                                   const float* __restrict__ distW,
                                                   const float* __restrict__ distB,
                                                   float* __restrict__ outA,
                                                   float* __restrict__ outB) {
    __shared__ __align__(16) float sm[4][256];
    int t = threadIdx.x;
    int w = t >> 6;
    int l = t & 63;
    int q = blockIdx.x * 4 + w;

    float4 hv = *reinterpret_cast<const float4*>(hidden + (size_t)q * 256 + l * 4);
    *reinterpret_cast<float4*>(&sm[w][l * 4]) = hv;
    __syncthreads();

    int v  = l & 15;
    int kc = l >> 4;
    float p = 0.f;
#pragma unroll
    for (int i = 0; i < 64; ++i) {
        int k = kc * 64 + i;
        p = fmaf(sm[w][k], dirW[k * VOCAB + v], p);
    }
    p += __shfl_xor(p, 16);
    p += __shfl_xor(p, 32);
    p += dirB[v];

    float m = p;
#pragma unroll
    for (int d = 1; d < 16; d <<= 1) m = fmaxf(m, __shfl_xor(m, d));
    float es = __expf(p - m);
    float ss = es;
#pragma unroll
    for (int d = 1; d < 16; d <<= 1) ss += __shfl_xor(ss, d);
    float outv = p - m - __logf(ss);
    if (l < 16) outA[(size_t)q * VOCAB + v] = outv;

    float pd = hv.x * distW[l * 4 + 0] + hv.y * distW[l * 4 + 1] +
               hv.z * distW[l * 4 + 2] + hv.w * distW[l * 4 + 3];
#pragma unroll
    for (int d = 1; d < 64; d <<= 1) pd += __shfl_xor(pd, d);
    if (l == 0) outB[q] = pd + distB[0];
}

extern "C" void kernel_launch(void* const* d_in, const int* in_sizes, int n_in,
                              void* d_out, int out_size, void* d_ws, size_t ws_size,
                              hipStream_t stream) {
    const float* x      = (const float*)d_in[0];
    const int*   ei     = (const int*)d_in[1];
    const int*   et     = (const int*)d_in[2];
    const int*   nest   = (const int*)d_in[3];
    const int*   food   = (const int*)d_in[4];
    const float* Wrel1  = (const float*)d_in[5];
    const float* Wroot1 = (const float*)d_in[6];
    const float* b1     = (const float*)d_in[7];
    const float* Wrel2  = (const float*)d_in[8];
    const float* Wroot2 = (const float*)d_in[9];
    const float* b2     = (const float*)d_in[10];
    const float* fcW    = (const float*)d_in[11];
    const float* fcB    = (const float*)d_in[12];
    const float* dirW   = (const float*)d_in[13];
    const float* dirB   = (const float*)d_in[14];
    const float* distW  = (const float*)d_in[15];
    const float* distB  = (const float*)d_in[16];

    char* ws = (char*)d_ws;
    size_t off = 0;
    auto alloc = [&](size_t bytes) {
        void* p = ws + off;
        off += (bytes + 255) & ~(size_t)255;
        return p;
    };
    float* S      = (float*)alloc((size_t)N_NODES * 512 * 4);   // 81.92 MB
    float* hA     = (float*)alloc((size_t)N_NODES * 128 * 4);   // 20.48 MB
    float* hB     = (float*)alloc((size_t)N_NODES * 128 * 4);   // 20.48 MB
    float* hidden = (float*)alloc((size_t)NB * 256 * 4);        //  4.19 MB
    // wtbuf aliases the bins histogram (bins dead after scanA; prep_w runs after scatter)
    short* wtbuf  = (short*)alloc((size_t)4 * 128 * KTOT * 2);  // 0.655 MB
    int*   bins   = (int*)wtbuf;                                // needs 0.64 MB
    int*   ptr    = (int*)alloc((size_t)(NBINS + 1) * 4);
    int*   cur    = (int*)alloc((size_t)(NBINS + 1) * 4);
    int*   bsum   = (int*)alloc(256 * 4);
    int*   boff   = (int*)alloc(256 * 4);
    int*   perm   = (int*)alloc((size_t)N_EDGES * 4);           //  2.56 MB

    short* wt1h = wtbuf;
    short* wt1l = wtbuf + 128 * KTOT;
    short* wt2h = wtbuf + 2 * 128 * KTOT;
    short* wt2l = wtbuf + 3 * 128 * KTOT;

    float* outA = (float*)d_out;             // [B,16]
    float* outB = (float*)d_out + NB * 16;   // [B]

    const int SCAN_BLKS = (NBINS + 1023) / 1024;   // 157

    // ---- CSR build (shared by both layers; uses bins region first) ----
    hipMemsetAsync(bins, 0, (size_t)NBINS * 4, stream);
    hist_kernel<<<(N_EDGES + 255) / 256, 256, 0, stream>>>(ei, et, bins);
    scanA_kernel<<<SCAN_BLKS, 256, 0, stream>>>(bins, ptr, bsum);
    scanB_kernel<<<1, 256, 0, stream>>>(bsum, boff, SCAN_BLKS);
    scanC_kernel<<<SCAN_BLKS, 256, 0, stream>>>(ptr, cur, boff);
    scatter_kernel<<<(N_EDGES + 255) / 256, 256, 0, stream>>>(ei, et, cur, perm);

    // ---- weight prep (overwrites dead bins region) ----
    prep_w<<<128, 256, 0, stream>>>(Wroot1, Wrel1, wt1h, wt1l);
    prep_w<<<128, 256, 0, stream>>>(Wroot2, Wrel2, wt2h, wt2l);

    // ---- layer 1 ----
    agg_csr_kernel<<<N_NODES / 4, 256, 0, stream>>>(x, ptr, perm, S, 0);
    gemm_layer_mfma<<<625, 256, 0, stream>>>(x, S, wt1h, wt1l, b1, hA, 0);

    // ---- layer 2 (inputs relu'd on the fly) ----
    agg_csr_kernel<<<N_NODES / 4, 256, 0, stream>>>(hA, ptr, perm, S, 1);
    gemm_layer_mfma<<<625, 256, 0, stream>>>(hA, S, wt2h, wt2l, b2, hB, 1);

    // ---- heads ----
    gemm_head<<<dim3(64, 4), 256, 0, stream>>>(hB, nest, food, fcW, fcB, hidden);
    head_kernel<<<NB / 4, 256, 0, stream>>>(hidden, dirW, dirB, distW, distB, outA, outB);
}

// Round 9
// 355.715 us; speedup vs baseline: 1.5383x; 1.0380x over previous
//
#include <hip/hip_runtime.h>

#define N_NODES 40000
#define N_EDGES 640000
#define N_REL   4
#define NBINS   (N_NODES * N_REL)   // 160000 (dst, rel) segments
#define EMB     128
#define HID     256
#define VOCAB   16
#define NB      4096
#define KTOT    640

typedef __attribute__((ext_vector_type(8))) short bf16x8;
typedef __attribute__((ext_vector_type(4))) float f32x4;

__device__ __forceinline__ short f2bf(float f) {
    union { float f; unsigned u; } x; x.f = f;
    unsigned r = x.u + 0x7fffu + ((x.u >> 16) & 1u);   // RNE to bf16
    return (short)(r >> 16);
}
__device__ __forceinline__ float bf2f(short b) {
    union { unsigned u; float f; } x; x.u = ((unsigned)(unsigned short)b) << 16;
    return x.f;
}

// ================= CSR build: histogram -> scan -> scatter =================

__global__ __launch_bounds__(256) void hist_kernel(const int* __restrict__ ei,
                                                   const int* __restrict__ et,
                                                   int* __restrict__ bins) {
    int e = blockIdx.x * blockDim.x + threadIdx.x;
    if (e < N_EDGES) {
        int dst = ei[N_EDGES + e];
        int r   = et[e];
        atomicAdd(&bins[dst * N_REL + r], 1);
    }
}

__global__ __launch_bounds__(256) void scanA_kernel(const int* __restrict__ bins,
                                                    int* __restrict__ ptr,
                                                    int* __restrict__ bsum) {
    __shared__ int wsum[4];
    int t    = threadIdx.x;
    int base = blockIdx.x * 1024 + t * 4;
    int v[4];
#pragma unroll
    for (int i = 0; i < 4; ++i) {
        int idx = base + i;
        v[i] = (idx < NBINS) ? bins[idx] : 0;
    }
    int tot  = v[0] + v[1] + v[2] + v[3];
    int lane = t & 63, w = t >> 6;
    int inc  = tot;
#pragma unroll
    for (int d = 1; d < 64; d <<= 1) {
        int n = __shfl_up(inc, d);
        if (lane >= d) inc += n;
    }
    if (lane == 63) wsum[w] = inc;
    __syncthreads();
    int woff = 0;
    for (int i = 0; i < w; ++i) woff += wsum[i];
    int run = woff + inc - tot;
#pragma unroll
    for (int i = 0; i < 4; ++i) {
        int idx = base + i;
        if (idx < NBINS) ptr[idx] = run;
        run += v[i];
    }
    if (t == 255) bsum[blockIdx.x] = woff + inc;
}

__global__ __launch_bounds__(256) void scanB_kernel(const int* __restrict__ bsum,
                                                    int* __restrict__ boff, int nblk) {
    __shared__ int sh[256];
    int t = threadIdx.x;
    int v = (t < nblk) ? bsum[t] : 0;
    sh[t] = v;
    __syncthreads();
    for (int d = 1; d < 256; d <<= 1) {
        int n = (t >= d) ? sh[t - d] : 0;
        __syncthreads();
        sh[t] += n;
        __syncthreads();
    }
    if (t < nblk) boff[t] = sh[t] - v;
}

__global__ __launch_bounds__(256) void scanC_kernel(int* __restrict__ ptr,
                                                    int* __restrict__ cur,
                                                    const int* __restrict__ boff) {
    int base = blockIdx.x * 1024 + threadIdx.x * 4;
    int off  = boff[blockIdx.x];
#pragma unroll
    for (int i = 0; i < 4; ++i) {
        int idx = base + i;
        if (idx < NBINS) {
            int p = ptr[idx] + off;
            ptr[idx] = p;
            cur[idx] = p;
        }
    }
    if (blockIdx.x == 0 && threadIdx.x == 0) ptr[NBINS] = N_EDGES;
}

__global__ __launch_bounds__(256) void scatter_kernel(const int* __restrict__ ei,
                                                      const int* __restrict__ et,
                                                      int* __restrict__ cur,
                                                      int* __restrict__ perm) {
    int e = blockIdx.x * blockDim.x + threadIdx.x;
    if (e < N_EDGES) {
        int src = ei[e];
        int dst = ei[N_EDGES + e];
        int r   = et[e];
        int pos = atomicAdd(&cur[dst * N_REL + r], 1);
        perm[pos] = src;
    }
}

// ============ segmented mean-aggregation: S[n,r,:] = mean X[src] ============
// One wave per node. The node's 4 relation segments are contiguous in perm;
// a 64-wide register window holds edge srcs (reloaded wave-uniformly when a
// batch crosses it). Per-relation loops accumulate with plain adds (2/edge),
// 4-deep load ILP. No relu: layer-1 GEMM epilogue stores relu'd h.
__global__ __launch_bounds__(256) void agg_csr_kernel(const float* __restrict__ X,
                                                      const int* __restrict__ ptr,
                                                      const int* __restrict__ perm,
                                                      float* __restrict__ S) {
    int node = blockIdx.x * 4 + (threadIdx.x >> 6);
    int l    = threadIdx.x & 63;

    int pr[5];
#pragma unroll
    for (int i = 0; i < 5; ++i) pr[i] = ptr[node * 4 + i];

    int wbase = pr[0];
    int srcs  = perm[min(wbase + l, N_EDGES - 1)];
    float* Sp = S + (size_t)node * 512 + l * 2;

#pragma unroll
    for (int r = 0; r < 4; ++r) {
        int s = pr[r], e = pr[r + 1];
        float ax = 0.f, ay = 0.f;
        for (int j = s; j < e; j += 4) {
            int hi = min(j + 3, e - 1);
            if (hi >= wbase + 64) {            // wave-uniform window reload
                wbase = j;
                srcs  = perm[min(wbase + l, N_EDGES - 1)];
            }
            float2 v[4]; bool val[4];
#pragma unroll
            for (int u = 0; u < 4; ++u) {
                int jj = j + u;
                val[u] = jj < e;
                int src = __shfl(srcs, (val[u] ? jj : j) - wbase);
                v[u] = *reinterpret_cast<const float2*>(X + (size_t)src * 128 + l * 2);
            }
#pragma unroll
            for (int u = 0; u < 4; ++u) {
                ax += val[u] ? v[u].x : 0.f;
                ay += val[u] ? v[u].y : 0.f;
            }
        }
        float sc = 1.0f / (float)max(e - s, 1);
        *reinterpret_cast<float2*>(Sp + r * 128) = make_float2(ax * sc, ay * sc);
    }
}

// ============ weight prep: W^T, split into bf16 hi/lo: Wt[col][640] ============
__global__ __launch_bounds__(256) void prep_w(const float* __restrict__ Wroot,
                                              const float* __restrict__ Wrel,
                                              short* __restrict__ Wth,
                                              short* __restrict__ Wtl) {
    int col = blockIdx.x;                       // 0..127
    for (int g = threadIdx.x; g < KTOT; g += 256) {
        float w = (g < 128) ? Wroot[(size_t)g * 128 + col]
                            : Wrel[(size_t)(g - 128) * 128 + col];
        short h  = f2bf(w);
        short lo = f2bf(w - bf2f(h));
        Wth[(size_t)col * KTOT + g] = h;
        Wtl[(size_t)col * KTOT + g] = lo;
    }
}

// ============ fused layer GEMM via split-bf16 MFMA ============
// C[n,j] = X[n]@Wroot + b + sum_r S[n,r]@Wrel[r]; optional relu on OUTPUT.
__global__ __launch_bounds__(256, 3) void gemm_layer_mfma(
        const float* __restrict__ X, const float* __restrict__ S,
        const short* __restrict__ Wth, const short* __restrict__ Wtl,
        const float* __restrict__ bias, float* __restrict__ C, int relu_out) {
    __shared__ __align__(16) short As_h[64 * 64];    //  8 KB
    __shared__ __align__(16) short As_l[64 * 64];    //  8 KB
    __shared__ __align__(16) short Bs_h[128 * 64];   // 16 KB  [col][k]
    __shared__ __align__(16) short Bs_l[128 * 64];   // 16 KB

    const int t   = threadIdx.x;
    const int rm  = blockIdx.x * 64;
    const int l   = t & 63, w = t >> 6;
    const int mh  = (w >> 1) * 32;        // wave row-half
    const int nh  = (w & 1) * 64;         // wave col-half
    const int r16 = l & 15, kch = l >> 4; // MFMA lane coords

    f32x4 acc[2][4];
#pragma unroll
    for (int mt = 0; mt < 2; ++mt)
#pragma unroll
        for (int nt = 0; nt < 4; ++nt)
            acc[mt][nt] = (f32x4){0.f, 0.f, 0.f, 0.f};

    for (int kt = 0; kt < 10; ++kt) {
        // ---- stage A: 64 rows x 64 k, fp32 -> bf16 hi/lo, swizzled ----
#pragma unroll
        for (int i = 0; i < 4; ++i) {
            int idx  = t + i * 256;        // 0..1023
            int row  = idx >> 4;           // 0..63
            int kc   = (idx & 15) * 4;     // 0..60
            int grow = rm + row;
            float4 v;
            if (kt < 2) {
                v = *reinterpret_cast<const float4*>(X + (size_t)grow * 128 + kt * 64 + kc);
            } else {
                v = *reinterpret_cast<const float4*>(S + (size_t)grow * 512 + (kt - 2) * 64 + kc);
            }
            short h0 = f2bf(v.x), h1 = f2bf(v.y), h2 = f2bf(v.z), h3 = f2bf(v.w);
            short l0 = f2bf(v.x - bf2f(h0)), l1 = f2bf(v.y - bf2f(h1));
            short l2 = f2bf(v.z - bf2f(h2)), l3 = f2bf(v.w - bf2f(h3));
            int off = ((row << 7) + (kc << 1)) ^ ((row & 7) << 4);
            *reinterpret_cast<short4*>((char*)As_h + off) = make_short4(h0, h1, h2, h3);
            *reinterpret_cast<short4*>((char*)As_l + off) = make_short4(l0, l1, l2, l3);
        }
        // ---- stage B: 128 cols x 64 k from pre-split W^T, swizzled ----
#pragma unroll
        for (int i = 0; i < 4; ++i) {
            int idx = t + i * 256;         // 0..1023
            int col = idx >> 3;            // 0..127
            int k0  = (idx & 7) * 8;       // 0..56
            size_t goff = (size_t)col * KTOT + kt * 64 + k0;
            bf16x8 hv = *reinterpret_cast<const bf16x8*>(Wth + goff);
            bf16x8 lv = *reinterpret_cast<const bf16x8*>(Wtl + goff);
            int off = ((col << 7) + (k0 << 1)) ^ ((col & 7) << 4);
            *reinterpret_cast<bf16x8*>((char*)Bs_h + off) = hv;
            *reinterpret_cast<bf16x8*>((char*)Bs_l + off) = lv;
        }
        __syncthreads();
        // ---- 2 x K32 MFMA steps ----
#pragma unroll
        for (int s = 0; s < 2; ++s) {
            int kb = s * 64 + kch * 16;    // byte offset of this lane's k-chunk
            bf16x8 ah[2], al[2], bh[4], bl[4];
#pragma unroll
            for (int mt = 0; mt < 2; ++mt) {
                int row = mh + mt * 16 + r16;
                int off = ((row << 7) + kb) ^ ((row & 7) << 4);
                ah[mt] = *reinterpret_cast<const bf16x8*>((const char*)As_h + off);
                al[mt] = *reinterpret_cast<const bf16x8*>((const char*)As_l + off);
            }
#pragma unroll
            for (int nt = 0; nt < 4; ++nt) {
                int col = nh + nt * 16 + r16;
                int off = ((col << 7) + kb) ^ ((col & 7) << 4);
                bh[nt] = *reinterpret_cast<const bf16x8*>((const char*)Bs_h + off);
                bl[nt] = *reinterpret_cast<const bf16x8*>((const char*)Bs_l + off);
            }
#pragma unroll
            for (int mt = 0; mt < 2; ++mt)
#pragma unroll
                for (int nt = 0; nt < 4; ++nt) {
                    acc[mt][nt] = __builtin_amdgcn_mfma_f32_16x16x32_bf16(ah[mt], bh[nt], acc[mt][nt], 0, 0, 0);
                    acc[mt][nt] = __builtin_amdgcn_mfma_f32_16x16x32_bf16(ah[mt], bl[nt], acc[mt][nt], 0, 0, 0);
                    acc[mt][nt] = __builtin_amdgcn_mfma_f32_16x16x32_bf16(al[mt], bh[nt], acc[mt][nt], 0, 0, 0);
                }
        }
        __syncthreads();
    }
    // ---- epilogue: C/D layout col=l&15, row=(l>>4)*4+r; optional relu ----
#pragma unroll
    for (int mt = 0; mt < 2; ++mt)
#pragma unroll
        for (int nt = 0; nt < 4; ++nt) {
            int col = nh + nt * 16 + r16;
            float bv = bias[col];
#pragma unroll
            for (int r = 0; r < 4; ++r) {
                int row = rm + mh + mt * 16 + kch * 4 + r;
                float o = acc[mt][nt][r] + bv;
                if (relu_out) o = fmaxf(o, 0.f);
                C[(size_t)row * 128 + col] = o;
            }
        }
}

// ========== head GEMM (fp32): gather(nest,food) fused, relu out ==========
#define FMA16()                                                                 \
    acc[0][0] = fmaf(a0, b.x, acc[0][0]); acc[0][1] = fmaf(a0, b.y, acc[0][1]); \
    acc[0][2] = fmaf(a0, b.z, acc[0][2]); acc[0][3] = fmaf(a0, b.w, acc[0][3]); \
    acc[1][0] = fmaf(a1, b.x, acc[1][0]); acc[1][1] = fmaf(a1, b.y, acc[1][1]); \
    acc[1][2] = fmaf(a1, b.z, acc[1][2]); acc[1][3] = fmaf(a1, b.w, acc[1][3]); \
    acc[2][0] = fmaf(a2, b.x, acc[2][0]); acc[2][1] = fmaf(a2, b.y, acc[2][1]); \
    acc[2][2] = fmaf(a2, b.z, acc[2][2]); acc[2][3] = fmaf(a2, b.w, acc[2][3]); \
    acc[3][0] = fmaf(a3, b.x, acc[3][0]); acc[3][1] = fmaf(a3, b.y, acc[3][1]); \
    acc[3][2] = fmaf(a3, b.z, acc[3][2]); acc[3][3] = fmaf(a3, b.w, acc[3][3])

#define KSTEP(J, AX)                                                \
    {                                                               \
        float4 b  = bq##J;                                          \
        float  a0 = aq0.AX, a1 = aq1.AX, a2 = aq2.AX, a3 = aq3.AX;  \
        FMA16();                                                    \
    }

#define INNER_K128(AS, BS)                                                     \
    _Pragma("unroll 2")                                                        \
    for (int kk = 0; kk < 128; kk += 4) {                                      \
        float4 aq0 = *reinterpret_cast<const float4*>(&AS[ty * 4 + 0][kk]);    \
        float4 aq1 = *reinterpret_cast<const float4*>(&AS[ty * 4 + 1][kk]);    \
        float4 aq2 = *reinterpret_cast<const float4*>(&AS[ty * 4 + 2][kk]);    \
        float4 aq3 = *reinterpret_cast<const float4*>(&AS[ty * 4 + 3][kk]);    \
        float4 bq0 = *reinterpret_cast<const float4*>(&BS[kk + 0][tx * 4]);    \
        float4 bq1 = *reinterpret_cast<const float4*>(&BS[kk + 1][tx * 4]);    \
        float4 bq2 = *reinterpret_cast<const float4*>(&BS[kk + 2][tx * 4]);    \
        float4 bq3 = *reinterpret_cast<const float4*>(&BS[kk + 3][tx * 4]);    \
        KSTEP(0, x); KSTEP(1, y); KSTEP(2, z); KSTEP(3, w);                    \
    }

__global__ __launch_bounds__(256) void gemm_head(const float* __restrict__ H,
                                                 const int* __restrict__ nest,
                                                 const int* __restrict__ food,
                                                 const float* __restrict__ W,
                                                 const float* __restrict__ bias,
                                                 float* __restrict__ C) {
    __shared__ __align__(16) float As[64][132];
    __shared__ __align__(16) float Bs[128][68];
    int t  = threadIdx.x;
    int rm = blockIdx.x * 64;
    int cn = blockIdx.y * 64;
    int ty = t >> 4, tx = t & 15;
    float acc[4][4];
#pragma unroll
    for (int i = 0; i < 4; ++i)
#pragma unroll
        for (int j = 0; j < 4; ++j) acc[i][j] = 0.f;

    for (int kt = 0; kt < 2; ++kt) {
        const int* idx = (kt == 0) ? nest : food;
#pragma unroll
        for (int i = 0; i < 8; ++i) {
            int idx4 = t + i * 256;
            int row  = idx4 >> 5;
            int kc4  = idx4 & 31;
            int node = idx[rm + row];
            *reinterpret_cast<float4*>(&As[row][kc4 * 4]) =
                *reinterpret_cast<const float4*>(H + (size_t)node * 128 + kc4 * 4);
        }
#pragma unroll
        for (int i = 0; i < 8; ++i) {
            int idx4 = t + i * 256;
            int kk   = idx4 >> 4;
            int j4   = idx4 & 15;
            *reinterpret_cast<float4*>(&Bs[kk][j4 * 4]) =
                *reinterpret_cast<const float4*>(W + (size_t)(kt * 128 + kk) * 256 + cn + j4 * 4);
        }
        __syncthreads();
        INNER_K128(As, Bs);
        __syncthreads();
    }
    float4 bv = *reinterpret_cast<const float4*>(bias + cn + tx * 4);
#pragma unroll
    for (int i = 0; i < 4; ++i) {
        int grow = rm + ty * 4 + i;
        float4 o;
        o.x = fmaxf(acc[i][0] + bv.x, 0.f); o.y = fmaxf(acc[i][1] + bv.y, 0.f);
        o.z = fmaxf(acc[i][2] + bv.z, 0.f); o.w = fmaxf(acc[i][3] + bv.w, 0.f);
        *reinterpret_cast<float4*>(C + (size_t)grow * 256 + cn + tx * 4) = o;
    }
}

// ====== heads: logits + log_softmax + dist, one wave per query ======
__global__ __launch_bounds__(256) void head_kernel(const float* __restrict__ hidden,
                                                   const float* __restrict__ dirW,
                                                   const float* __restrict__ dirB,
                                                   const float* __restrict__ distW,
                                                   const float* __restrict__ distB,
                                                   float* __restrict__ outA,
                                                   float* __restrict__ outB) {
    __shared__ __align__(16) float sm[4][256];
    int t = threadIdx.x;
    int w = t >> 6;
    int l = t & 63;
    int q = blockIdx.x * 4 + w;

    float4 hv = *reinterpret_cast<const float4*>(hidden + (size_t)q * 256 + l * 4);
    *reinterpret_cast<float4*>(&sm[w][l * 4]) = hv;
    __syncthreads();

    int v  = l & 15;
    int kc = l >> 4;
    float p = 0.f;
#pragma unroll
    for (int i = 0; i < 64; ++i) {
        int k = kc * 64 + i;
        p = fmaf(sm[w][k], dirW[k * VOCAB + v], p);
    }
    p += __shfl_xor(p, 16);
    p += __shfl_xor(p, 32);
    p += dirB[v];

    float m = p;
#pragma unroll
    for (int d = 1; d < 16; d <<= 1) m = fmaxf(m, __shfl_xor(m, d));
    float es = __expf(p - m);
    float ss = es;
#pragma unroll
    for (int d = 1; d < 16; d <<= 1) ss += __shfl_xor(ss, d);
    float outv = p - m - __logf(ss);
    if (l < 16) outA[(size_t)q * VOCAB + v] = outv;

    float pd = hv.x * distW[l * 4 + 0] + hv.y * distW[l * 4 + 1] +
               hv.z * distW[l * 4 + 2] + hv.w * distW[l * 4 + 3];
#pragma unroll
    for (int d = 1; d < 64; d <<= 1) pd += __shfl_xor(pd, d);
    if (l == 0) outB[q] = pd + distB[0];
}

extern "C" void kernel_launch(void* const* d_in, const int* in_sizes, int n_in,
                              void* d_out, int out_size, void* d_ws, size_t ws_size,
                              hipStream_t stream) {
    const float* x      = (const float*)d_in[0];
    const int*   ei     = (const int*)d_in[1];
    const int*   et     = (const int*)d_in[2];
    const int*   nest   = (const int*)d_in[3];
    const int*   food   = (const int*)d_in[4];
    const float* Wrel1  = (const float*)d_in[5];
    const float* Wroot1 = (const float*)d_in[6];
    const float* b1     = (const float*)d_in[7];
    const float* Wrel2  = (const float*)d_in[8];
    const float* Wroot2 = (const float*)d_in[9];
    const float* b2     = (const float*)d_in[10];
    const float* fcW    = (const float*)d_in[11];
    const float* fcB    = (const float*)d_in[12];
    const float* dirW   = (const float*)d_in[13];
    const float* dirB   = (const float*)d_in[14];
    const float* distW  = (const float*)d_in[15];
    const float* distB  = (const float*)d_in[16];

    char* ws = (char*)d_ws;
    size_t off = 0;
    auto alloc = [&](size_t bytes) {
        void* p = ws + off;
        off += (bytes + 255) & ~(size_t)255;
        return p;
    };
    float* S      = (float*)alloc((size_t)N_NODES * 512 * 4);   // 81.92 MB
    float* hA     = (float*)alloc((size_t)N_NODES * 128 * 4);   // 20.48 MB
    float* hB     = (float*)alloc((size_t)N_NODES * 128 * 4);   // 20.48 MB
    float* hidden = (float*)alloc((size_t)NB * 256 * 4);        //  4.19 MB
    // wtbuf aliases the bins histogram (bins dead after scanA; prep_w runs after scatter)
    short* wtbuf  = (short*)alloc((size_t)4 * 128 * KTOT * 2);  // 0.655 MB
    int*   bins   = (int*)wtbuf;                                // needs 0.64 MB
    int*   ptr    = (int*)alloc((size_t)(NBINS + 1) * 4);
    int*   cur    = (int*)alloc((size_t)(NBINS + 1) * 4);
    int*   bsum   = (int*)alloc(256 * 4);
    int*   boff   = (int*)alloc(256 * 4);
    int*   perm   = (int*)alloc((size_t)N_EDGES * 4);           //  2.56 MB

    short* wt1h = wtbuf;
    short* wt1l = wtbuf + 128 * KTOT;
    short* wt2h = wtbuf + 2 * 128 * KTOT;
    short* wt2l = wtbuf + 3 * 128 * KTOT;

    float* outA = (float*)d_out;             // [B,16]
    float* outB = (float*)d_out + NB * 16;   // [B]

    const int SCAN_BLKS = (NBINS + 1023) / 1024;   // 157

    // ---- CSR build (shared by both layers; uses bins region first) ----
    hipMemsetAsync(bins, 0, (size_t)NBINS * 4, stream);
    hist_kernel<<<(N_EDGES + 255) / 256, 256, 0, stream>>>(ei, et, bins);
    scanA_kernel<<<SCAN_BLKS, 256, 0, stream>>>(bins, ptr, bsum);
    scanB_kernel<<<1, 256, 0, stream>>>(bsum, boff, SCAN_BLKS);
    scanC_kernel<<<SCAN_BLKS, 256, 0, stream>>>(ptr, cur, boff);
    scatter_kernel<<<(N_EDGES + 255) / 256, 256, 0, stream>>>(ei, et, cur, perm);

    // ---- weight prep (overwrites dead bins region) ----
    prep_w<<<128, 256, 0, stream>>>(Wroot1, Wrel1, wt1h, wt1l);
    prep_w<<<128, 256, 0, stream>>>(Wroot2, Wrel2, wt2h, wt2l);

    // ---- layer 1 (epilogue relu -> hA = relu(conv1)) ----
    agg_csr_kernel<<<N_NODES / 4, 256, 0, stream>>>(x, ptr, perm, S);
    gemm_layer_mfma<<<625, 256, 0, stream>>>(x, S, wt1h, wt1l, b1, hA, 1);

    // ---- layer 2 (hA already relu'd) ----
    agg_csr_kernel<<<N_NODES / 4, 256, 0, stream>>>(hA, ptr, perm, S);
    gemm_layer_mfma<<<625, 256, 0, stream>>>(hA, S, wt2h, wt2l, b2, hB, 0);

    // ---- heads ----
    gemm_head<<<dim3(64, 4), 256, 0, stream>>>(hB, nest, food, fcW, fcB, hidden);
    head_kernel<<<NB / 4, 256, 0, stream>>>(hidden, dirW, dirB, distW, distB, outA, outB);
}

// Round 11
// 334.549 us; speedup vs baseline: 1.6356x; 1.0633x over previous
//
#include <hip/hip_runtime.h>

#define N_NODES 40000
#define N_EDGES 640000
#define N_REL   4
#define NBINS   (N_NODES * N_REL)   // 160000 (dst, rel) segments
#define EMB     128
#define HID     256
#define VOCAB   16
#define NB      4096
#define KTOT    640

typedef __attribute__((ext_vector_type(8))) short bf16x8;
typedef __attribute__((ext_vector_type(4))) float f32x4;

__device__ __forceinline__ short f2bf(float f) {
    union { float f; unsigned u; } x; x.f = f;
    unsigned r = x.u + 0x7fffu + ((x.u >> 16) & 1u);   // RNE to bf16
    return (short)(r >> 16);
}
__device__ __forceinline__ float bf2f(short b) {
    union { unsigned u; float f; } x; x.u = ((unsigned)(unsigned short)b) << 16;
    return x.f;
}

// ================= CSR build: histogram -> scan -> scatter =================

__global__ __launch_bounds__(256) void hist_kernel(const int* __restrict__ ei,
                                                   const int* __restrict__ et,
                                                   int* __restrict__ bins) {
    int e = blockIdx.x * blockDim.x + threadIdx.x;
    if (e < N_EDGES) {
        int dst = ei[N_EDGES + e];
        int r   = et[e];
        atomicAdd(&bins[dst * N_REL + r], 1);
    }
}

__global__ __launch_bounds__(256) void scanA_kernel(const int* __restrict__ bins,
                                                    int* __restrict__ ptr,
                                                    int* __restrict__ bsum) {
    __shared__ int wsum[4];
    int t    = threadIdx.x;
    int base = blockIdx.x * 1024 + t * 4;
    int v[4];
#pragma unroll
    for (int i = 0; i < 4; ++i) {
        int idx = base + i;
        v[i] = (idx < NBINS) ? bins[idx] : 0;
    }
    int tot  = v[0] + v[1] + v[2] + v[3];
    int lane = t & 63, w = t >> 6;
    int inc  = tot;
#pragma unroll
    for (int d = 1; d < 64; d <<= 1) {
        int n = __shfl_up(inc, d);
        if (lane >= d) inc += n;
    }
    if (lane == 63) wsum[w] = inc;
    __syncthreads();
    int woff = 0;
    for (int i = 0; i < w; ++i) woff += wsum[i];
    int run = woff + inc - tot;
#pragma unroll
    for (int i = 0; i < 4; ++i) {
        int idx = base + i;
        if (idx < NBINS) ptr[idx] = run;
        run += v[i];
    }
    if (t == 255) bsum[blockIdx.x] = woff + inc;
}

__global__ __launch_bounds__(256) void scanB_kernel(const int* __restrict__ bsum,
                                                    int* __restrict__ boff, int nblk) {
    __shared__ int sh[256];
    int t = threadIdx.x;
    int v = (t < nblk) ? bsum[t] : 0;
    sh[t] = v;
    __syncthreads();
    for (int d = 1; d < 256; d <<= 1) {
        int n = (t >= d) ? sh[t - d] : 0;
        __syncthreads();
        sh[t] += n;
        __syncthreads();
    }
    if (t < nblk) boff[t] = sh[t] - v;
}

__global__ __launch_bounds__(256) void scanC_kernel(int* __restrict__ ptr,
                                                    int* __restrict__ cur,
                                                    const int* __restrict__ boff) {
    int base = blockIdx.x * 1024 + threadIdx.x * 4;
    int off  = boff[blockIdx.x];
#pragma unroll
    for (int i = 0; i < 4; ++i) {
        int idx = base + i;
        if (idx < NBINS) {
            int p = ptr[idx] + off;
            ptr[idx] = p;
            cur[idx] = p;
        }
    }
    if (blockIdx.x == 0 && threadIdx.x == 0) ptr[NBINS] = N_EDGES;
}

__global__ __launch_bounds__(256) void scatter_kernel(const int* __restrict__ ei,
                                                      const int* __restrict__ et,
                                                      int* __restrict__ cur,
                                                      int* __restrict__ perm) {
    int e = blockIdx.x * blockDim.x + threadIdx.x;
    if (e < N_EDGES) {
        int src = ei[e];
        int dst = ei[N_EDGES + e];
        int r   = et[e];
        int pos = atomicAdd(&cur[dst * N_REL + r], 1);
        perm[pos] = src;
    }
}

// ============ fp32 -> bf16 shadow copy (for the gather) ============
__global__ __launch_bounds__(256) void cvt_kernel(const float* __restrict__ in,
                                                  unsigned short* __restrict__ out) {
    int i = blockIdx.x * blockDim.x + threadIdx.x;   // per 4 elems
    float4 v = *reinterpret_cast<const float4*>(in + (size_t)i * 4);
    ushort4 o;
    o.x = (unsigned short)f2bf(v.x); o.y = (unsigned short)f2bf(v.y);
    o.z = (unsigned short)f2bf(v.z); o.w = (unsigned short)f2bf(v.w);
    *reinterpret_cast<ushort4*>(out + (size_t)i * 4) = o;
}

// ============ segmented mean-aggregation: S[n,r,:] = mean Xb[src] ============
// One wave per node; gathers bf16 rows (256B/edge, half the fp32 traffic),
// accumulates fp32. Segments contiguous in perm; 64-wide register window.
__global__ __launch_bounds__(256) void agg_csr_kernel(const unsigned short* __restrict__ Xb,
                                                      const int* __restrict__ ptr,
                                                      const int* __restrict__ perm,
                                                      float* __restrict__ S) {
    int node = blockIdx.x * 4 + (threadIdx.x >> 6);
    int l    = threadIdx.x & 63;

    int pr[5];
#pragma unroll
    for (int i = 0; i < 5; ++i) pr[i] = ptr[node * 4 + i];

    int wbase = pr[0];
    int srcs  = perm[min(wbase + l, N_EDGES - 1)];
    float* Sp = S + (size_t)node * 512 + l * 2;

#pragma unroll
    for (int r = 0; r < 4; ++r) {
        int s = pr[r], e = pr[r + 1];
        float ax = 0.f, ay = 0.f;
        for (int j = s; j < e; j += 4) {
            int hi = min(j + 3, e - 1);
            if (hi >= wbase + 64) {            // wave-uniform window reload
                wbase = j;
                srcs  = perm[min(wbase + l, N_EDGES - 1)];
            }
            ushort2 v[4]; bool val[4];
#pragma unroll
            for (int u = 0; u < 4; ++u) {
                int jj = j + u;
                val[u] = jj < e;
                int src = __shfl(srcs, (val[u] ? jj : j) - wbase);
                v[u] = *reinterpret_cast<const ushort2*>(Xb + (size_t)src * 128 + l * 2);
            }
#pragma unroll
            for (int u = 0; u < 4; ++u) {
                ax += val[u] ? bf2f((short)v[u].x) : 0.f;
                ay += val[u] ? bf2f((short)v[u].y) : 0.f;
            }
        }
        float sc = 1.0f / (float)max(e - s, 1);
        *reinterpret_cast<float2*>(Sp + r * 128) = make_float2(ax * sc, ay * sc);
    }
}

// ============ weight prep: W^T, split into bf16 hi/lo: Wt[col][640] ============
__global__ __launch_bounds__(256) void prep_w(const float* __restrict__ Wroot,
                                              const float* __restrict__ Wrel,
                                              short* __restrict__ Wth,
                                              short* __restrict__ Wtl) {
    int col = blockIdx.x;                       // 0..127
    for (int g = threadIdx.x; g < KTOT; g += 256) {
        float w = (g < 128) ? Wroot[(size_t)g * 128 + col]
                            : Wrel[(size_t)(g - 128) * 128 + col];
        short h  = f2bf(w);
        short lo = f2bf(w - bf2f(h));
        Wth[(size_t)col * KTOT + g] = h;
        Wtl[(size_t)col * KTOT + g] = lo;
    }
}

// ============ fused layer GEMM via split-bf16 MFMA ============
// C[n,j] = X[n]@Wroot + b + sum_r S[n,r]@Wrel[r]; optional relu on OUTPUT.
__global__ __launch_bounds__(256, 3) void gemm_layer_mfma(
        const float* __restrict__ X, const float* __restrict__ S,
        const short* __restrict__ Wth, const short* __restrict__ Wtl,
        const float* __restrict__ bias, float* __restrict__ C, int relu_out) {
    __shared__ __align__(16) short As_h[64 * 64];    //  8 KB
    __shared__ __align__(16) short As_l[64 * 64];    //  8 KB
    __shared__ __align__(16) short Bs_h[128 * 64];   // 16 KB  [col][k]
    __shared__ __align__(16) short Bs_l[128 * 64];   // 16 KB

    const int t   = threadIdx.x;
    const int rm  = blockIdx.x * 64;
    const int l   = t & 63, w = t >> 6;
    const int mh  = (w >> 1) * 32;        // wave row-half
    const int nh  = (w & 1) * 64;         // wave col-half
    const int r16 = l & 15, kch = l >> 4; // MFMA lane coords

    f32x4 acc[2][4];
#pragma unroll
    for (int mt = 0; mt < 2; ++mt)
#pragma unroll
        for (int nt = 0; nt < 4; ++nt)
            acc[mt][nt] = (f32x4){0.f, 0.f, 0.f, 0.f};

    for (int kt = 0; kt < 10; ++kt) {
        // ---- stage A: 64 rows x 64 k, fp32 -> bf16 hi/lo, swizzled ----
#pragma unroll
        for (int i = 0; i < 4; ++i) {
            int idx  = t + i * 256;        // 0..1023
            int row  = idx >> 4;           // 0..63
            int kc   = (idx & 15) * 4;     // 0..60
            int grow = rm + row;
            float4 v;
            if (kt < 2) {
                v = *reinterpret_cast<const float4*>(X + (size_t)grow * 128 + kt * 64 + kc);
            } else {
                v = *reinterpret_cast<const float4*>(S + (size_t)grow * 512 + (kt - 2) * 64 + kc);
            }
            short h0 = f2bf(v.x), h1 = f2bf(v.y), h2 = f2bf(v.z), h3 = f2bf(v.w);
            short l0 = f2bf(v.x - bf2f(h0)), l1 = f2bf(v.y - bf2f(h1));
            short l2 = f2bf(v.z - bf2f(h2)), l3 = f2bf(v.w - bf2f(h3));
            int off = ((row << 7) + (kc << 1)) ^ ((row & 7) << 4);
            *reinterpret_cast<short4*>((char*)As_h + off) = make_short4(h0, h1, h2, h3);
            *reinterpret_cast<short4*>((char*)As_l + off) = make_short4(l0, l1, l2, l3);
        }
        // ---- stage B: 128 cols x 64 k from pre-split W^T, swizzled ----
#pragma unroll
        for (int i = 0; i < 4; ++i) {
            int idx = t + i * 256;         // 0..1023
            int col = idx >> 3;            // 0..127
            int k0  = (idx & 7) * 8;       // 0..56
            size_t goff = (size_t)col * KTOT + kt * 64 + k0;
            bf16x8 hv = *reinterpret_cast<const bf16x8*>(Wth + goff);
            bf16x8 lv = *reinterpret_cast<const bf16x8*>(Wtl + goff);
            int off = ((col << 7) + (k0 << 1)) ^ ((col & 7) << 4);
            *reinterpret_cast<bf16x8*>((char*)Bs_h + off) = hv;
            *reinterpret_cast<bf16x8*>((char*)Bs_l + off) = lv;
        }
        __syncthreads();
        // ---- 2 x K32 MFMA steps ----
#pragma unroll
        for (int s = 0; s < 2; ++s) {
            int kb = s * 64 + kch * 16;    // byte offset of this lane's k-chunk
            bf16x8 ah[2], al[2], bh[4], bl[4];
#pragma unroll
            for (int mt = 0; mt < 2; ++mt) {
                int row = mh + mt * 16 + r16;
                int off = ((row << 7) + kb) ^ ((row & 7) << 4);
                ah[mt] = *reinterpret_cast<const bf16x8*>((const char*)As_h + off);
                al[mt] = *reinterpret_cast<const bf16x8*>((const char*)As_l + off);
            }
#pragma unroll
            for (int nt = 0; nt < 4; ++nt) {
                int col = nh + nt * 16 + r16;
                int off = ((col << 7) + kb) ^ ((col & 7) << 4);
                bh[nt] = *reinterpret_cast<const bf16x8*>((const char*)Bs_h + off);
                bl[nt] = *reinterpret_cast<const bf16x8*>((const char*)Bs_l + off);
            }
#pragma unroll
            for (int mt = 0; mt < 2; ++mt)
#pragma unroll
                for (int nt = 0; nt < 4; ++nt) {
                    acc[mt][nt] = __builtin_amdgcn_mfma_f32_16x16x32_bf16(ah[mt], bh[nt], acc[mt][nt], 0, 0, 0);
                    acc[mt][nt] = __builtin_amdgcn_mfma_f32_16x16x32_bf16(ah[mt], bl[nt], acc[mt][nt], 0, 0, 0);
                    acc[mt][nt] = __builtin_amdgcn_mfma_f32_16x16x32_bf16(al[mt], bh[nt], acc[mt][nt], 0, 0, 0);
                }
        }
        __syncthreads();
    }
    // ---- epilogue: C/D layout col=l&15, row=(l>>4)*4+r; optional relu ----
#pragma unroll
    for (int mt = 0; mt < 2; ++mt)
#pragma unroll
        for (int nt = 0; nt < 4; ++nt) {
            int col = nh + nt * 16 + r16;
            float bv = bias[col];
#pragma unroll
            for (int r = 0; r < 4; ++r) {
                int row = rm + mh + mt * 16 + kch * 4 + r;
                float o = acc[mt][nt][r] + bv;
                if (relu_out) o = fmaxf(o, 0.f);
                C[(size_t)row * 128 + col] = o;
            }
        }
}

// ========== head GEMM (fp32): gather(nest,food) fused, relu out ==========
#define FMA16()                                                                 \
    acc[0][0] = fmaf(a0, b.x, acc[0][0]); acc[0][1] = fmaf(a0, b.y, acc[0][1]); \
    acc[0][2] = fmaf(a0, b.z, acc[0][2]); acc[0][3] = fmaf(a0, b.w, acc[0][3]); \
    acc[1][0] = fmaf(a1, b.x, acc[1][0]); acc[1][1] = fmaf(a1, b.y, acc[1][1]); \
    acc[1][2] = fmaf(a1, b.z, acc[1][2]); acc[1][3] = fmaf(a1, b.w, acc[1][3]); \
    acc[2][0] = fmaf(a2, b.x, acc[2][0]); acc[2][1] = fmaf(a2, b.y, acc[2][1]); \
    acc[2][2] = fmaf(a2, b.z, acc[2][2]); acc[2][3] = fmaf(a2, b.w, acc[2][3]); \
    acc[3][0] = fmaf(a3, b.x, acc[3][0]); acc[3][1] = fmaf(a3, b.y, acc[3][1]); \
    acc[3][2] = fmaf(a3, b.z, acc[3][2]); acc[3][3] = fmaf(a3, b.w, acc[3][3])

#define KSTEP(J, AX)                                                \
    {                                                               \
        float4 b  = bq##J;                                          \
        float  a0 = aq0.AX, a1 = aq1.AX, a2 = aq2.AX, a3 = aq3.AX;  \
        FMA16();                                                    \
    }

#define INNER_K128(AS, BS)                                                     \
    _Pragma("unroll 2")                                                        \
    for (int kk = 0; kk < 128; kk += 4) {                                      \
        float4 aq0 = *reinterpret_cast<const float4*>(&AS[ty * 4 + 0][kk]);    \
        float4 aq1 = *reinterpret_cast<const float4*>(&AS[ty * 4 + 1][kk]);    \
        float4 aq2 = *reinterpret_cast<const float4*>(&AS[ty * 4 + 2][kk]);    \
        float4 aq3 = *reinterpret_cast<const float4*>(&AS[ty * 4 + 3][kk]);    \
        float4 bq0 = *reinterpret_cast<const float4*>(&BS[kk + 0][tx * 4]);    \
        float4 bq1 = *reinterpret_cast<const float4*>(&BS[kk + 1][tx * 4]);    \
        float4 bq2 = *reinterpret_cast<const float4*>(&BS[kk + 2][tx * 4]);    \
        float4 bq3 = *reinterpret_cast<const float4*>(&BS[kk + 3][tx * 4]);    \
        KSTEP(0, x); KSTEP(1, y); KSTEP(2, z); KSTEP(3, w);                    \
    }

__global__ __launch_bounds__(256) void gemm_head(const float* __restrict__ H,
                                                 const int* __restrict__ nest,
                                                 const int* __restrict__ food,
                                                 const float* __restrict__ W,
                                                 const float* __restrict__ bias,
                                                 float* __restrict__ C) {
    __shared__ __align__(16) float As[64][132];
    __shared__ __align__(16) float Bs[128][68];
    int t  = threadIdx.x;
    int rm = blockIdx.x * 64;
    int cn = blockIdx.y * 64;
    int ty = t >> 4, tx = t & 15;
    float acc[4][4];
#pragma unroll
    for (int i = 0; i < 4; ++i)
#pragma unroll
        for (int j = 0; j < 4; ++j) acc[i][j] = 0.f;

    for (int kt = 0; kt < 2; ++kt) {
        const int* idx = (kt == 0) ? nest : food;
#pragma unroll
        for (int i = 0; i < 8; ++i) {
            int idx4 = t + i * 256;
            int row  = idx4 >> 5;
            int kc4  = idx4 & 31;
            int node = idx[rm + row];
            *reinterpret_cast<float4*>(&As[row][kc4 * 4]) =
                *reinterpret_cast<const float4*>(H + (size_t)node * 128 + kc4 * 4);
        }
#pragma unroll
        for (int i = 0; i < 8; ++i) {
            int idx4 = t + i * 256;
            int kk   = idx4 >> 4;
            int j4   = idx4 & 15;
            *reinterpret_cast<float4*>(&Bs[kk][j4 * 4]) =
                *reinterpret_cast<const float4*>(W + (size_t)(kt * 128 + kk) * 256 + cn + j4 * 4);
        }
        __syncthreads();
        INNER_K128(As, Bs);
        __syncthreads();
    }
    float4 bv = *reinterpret_cast<const float4*>(bias + cn + tx * 4);
#pragma unroll
    for (int i = 0; i < 4; ++i) {
        int grow = rm + ty * 4 + i;
        float4 o;
        o.x = fmaxf(acc[i][0] + bv.x, 0.f); o.y = fmaxf(acc[i][1] + bv.y, 0.f);
        o.z = fmaxf(acc[i][2] + bv.z, 0.f); o.w = fmaxf(acc[i][3] + bv.w, 0.f);
        *reinterpret_cast<float4*>(C + (size_t)grow * 256 + cn + tx * 4) = o;
    }
}

// ====== heads: logits + log_softmax + dist, one wave per query ======
__global__ __launch_bounds__(256) void head_kernel(const float* __restrict__ hidden,
                                                   const float* __restrict__ dirW,
                                                   const float* __restrict__ dirB,
                                                   const float* __restrict__ distW,
                                                   const float* __restrict__ distB,
                                                   float* __restrict__ outA,
                                                   float* __restrict__ outB) {
    __shared__ __align__(16) float sm[4][256];
    int t = threadIdx.x;
    int w = t >> 6;
    int l = t & 63;
    int q = blockIdx.x * 4 + w;

    float4 hv = *reinterpret_cast<const float4*>(hidden + (size_t)q * 256 + l * 4);
    *reinterpret_cast<float4*>(&sm[w][l * 4]) = hv;
    __syncthreads();

    int v  = l & 15;
    int kc = l >> 4;
    float p = 0.f;
#pragma unroll
    for (int i = 0; i < 64; ++i) {
        int k = kc * 64 + i;
        p = fmaf(sm[w][k], dirW[k * VOCAB + v], p);
    }
    p += __shfl_xor(p, 16);
    p += __shfl_xor(p, 32);
    p += dirB[v];

    float m = p;
#pragma unroll
    for (int d = 1; d < 16; d <<= 1) m = fmaxf(m, __shfl_xor(m, d));
    float es = __expf(p - m);
    float ss = es;
#pragma unroll
    for (int d = 1; d < 16; d <<= 1) ss += __shfl_xor(ss, d);
    float outv = p - m - __logf(ss);
    if (l < 16) outA[(size_t)q * VOCAB + v] = outv;

    float pd = hv.x * distW[l * 4 + 0] + hv.y * distW[l * 4 + 1] +
               hv.z * distW[l * 4 + 2] + hv.w * distW[l * 4 + 3];
#pragma unroll
    for (int d = 1; d < 64; d <<= 1) pd += __shfl_xor(pd, d);
    if (l == 0) outB[q] = pd + distB[0];
}

extern "C" void kernel_launch(void* const* d_in, const int* in_sizes, int n_in,
                              void* d_out, int out_size, void* d_ws, size_t ws_size,
                              hipStream_t stream) {
    const float* x      = (const float*)d_in[0];
    const int*   ei     = (const int*)d_in[1];
    const int*   et     = (const int*)d_in[2];
    const int*   nest   = (const int*)d_in[3];
    const int*   food   = (const int*)d_in[4];
    const float* Wrel1  = (const float*)d_in[5];
    const float* Wroot1 = (const float*)d_in[6];
    const float* b1     = (const float*)d_in[7];
    const float* Wrel2  = (const float*)d_in[8];
    const float* Wroot2 = (const float*)d_in[9];
    const float* b2     = (const float*)d_in[10];
    const float* fcW    = (const float*)d_in[11];
    const float* fcB    = (const float*)d_in[12];
    const float* dirW   = (const float*)d_in[13];
    const float* dirB   = (const float*)d_in[14];
    const float* distW  = (const float*)d_in[15];
    const float* distB  = (const float*)d_in[16];

    char* ws = (char*)d_ws;
    size_t off = 0;
    auto alloc = [&](size_t bytes) {
        void* p = ws + off;
        off += (bytes + 255) & ~(size_t)255;
        return p;
    };
    float* S      = (float*)alloc((size_t)N_NODES * 512 * 4);   // 81.92 MB
    float* hA     = (float*)alloc((size_t)N_NODES * 128 * 4);   // 20.48 MB
    float* hB     = (float*)alloc((size_t)N_NODES * 128 * 4);   // 20.48 MB
    float* hidden = (float*)alloc((size_t)NB * 256 * 4);        //  4.19 MB
    // wtbuf aliases the bins histogram (bins dead after scanA; prep_w runs after scatter)
    short* wtbuf  = (short*)alloc((size_t)4 * 128 * KTOT * 2);  // 0.655 MB
    int*   bins   = (int*)wtbuf;                                // needs 0.64 MB
    int*   ptr    = (int*)alloc((size_t)(NBINS + 1) * 4);
    int*   cur    = (int*)alloc((size_t)(NBINS + 1) * 4);
    int*   bsum   = (int*)alloc(256 * 4);
    int*   boff   = (int*)alloc(256 * 4);
    int*   perm   = (int*)alloc((size_t)N_EDGES * 4);           //  2.56 MB

    // bf16 gather shadow (10.24 MB) aliased over hB: hB is only written by
    // gemm-2, which runs AFTER the last read of the shadow (agg-2).
    unsigned short* xb = (unsigned short*)hB;

    short* wt1h = wtbuf;
    short* wt1l = wtbuf + 128 * KTOT;
    short* wt2h = wtbuf + 2 * 128 * KTOT;
    short* wt2l = wtbuf + 3 * 128 * KTOT;

    float* outA = (float*)d_out;             // [B,16]
    float* outB = (float*)d_out + NB * 16;   // [B]

    const int SCAN_BLKS = (NBINS + 1023) / 1024;   // 157
    const int CVT_BLKS  = (N_NODES * 128 / 4) / 256;   // 5000

    // ---- CSR build (shared by both layers; uses bins region first) ----
    hipMemsetAsync(bins, 0, (size_t)NBINS * 4, stream);
    hist_kernel<<<(N_EDGES + 255) / 256, 256, 0, stream>>>(ei, et, bins);
    scanA_kernel<<<SCAN_BLKS, 256, 0, stream>>>(bins, ptr, bsum);
    scanB_kernel<<<1, 256, 0, stream>>>(bsum, boff, SCAN_BLKS);
    scanC_kernel<<<SCAN_BLKS, 256, 0, stream>>>(ptr, cur, boff);
    scatter_kernel<<<(N_EDGES + 255) / 256, 256, 0, stream>>>(ei, et, cur, perm);

    // ---- weight prep (overwrites dead bins region) ----
    prep_w<<<128, 256, 0, stream>>>(Wroot1, Wrel1, wt1h, wt1l);
    prep_w<<<128, 256, 0, stream>>>(Wroot2, Wrel2, wt2h, wt2l);

    // ---- layer 1: bf16 shadow of x -> agg -> GEMM (epilogue relu) ----
    cvt_kernel<<<CVT_BLKS, 256, 0, stream>>>(x, xb);
    agg_csr_kernel<<<N_NODES / 4, 256, 0, stream>>>(xb, ptr, perm, S);
    gemm_layer_mfma<<<625, 256, 0, stream>>>(x, S, wt1h, wt1l, b1, hA, 1);

    // ---- layer 2: bf16 shadow of relu(h1) -> agg -> GEMM ----
    cvt_kernel<<<CVT_BLKS, 256, 0, stream>>>(hA, xb);
    agg_csr_kernel<<<N_NODES / 4, 256, 0, stream>>>(xb, ptr, perm, S);
    gemm_layer_mfma<<<625, 256, 0, stream>>>(hA, S, wt2h, wt2l, b2, hB, 0);

    // ---- heads ----
    gemm_head<<<dim3(64, 4), 256, 0, stream>>>(hB, nest, food, fcW, fcB, hidden);
    head_kernel<<<NB / 4, 256, 0, stream>>>(hidden, dirW, dirB, distW, distB, outA, outB);
}

// Round 12
// 304.833 us; speedup vs baseline: 1.7951x; 1.0975x over previous
//
#include <hip/hip_runtime.h>

#define N_NODES 40000
#define N_EDGES 640000
#define N_REL   4
#define NBINS   (N_NODES * N_REL)   // 160000 (dst, rel) segments
#define EMB     128
#define HID     256
#define VOCAB   16
#define NB      4096
#define KTOT    640

typedef __attribute__((ext_vector_type(8))) short bf16x8;
typedef __attribute__((ext_vector_type(4))) float f32x4;

__device__ __forceinline__ short f2bf(float f) {
    union { float f; unsigned u; } x; x.f = f;
    unsigned r = x.u + 0x7fffu + ((x.u >> 16) & 1u);   // RNE to bf16
    return (short)(r >> 16);
}
__device__ __forceinline__ float bf2f(short b) {
    union { unsigned u; float f; } x; x.u = ((unsigned)(unsigned short)b) << 16;
    return x.f;
}

// ================= CSR build: histogram -> scan -> scatter =================
// 4 edges/thread: int4-coalesced loads + 4 independent atomic chains (ILP).

__global__ __launch_bounds__(256) void hist_kernel(const int* __restrict__ ei,
                                                   const int* __restrict__ et,
                                                   int* __restrict__ bins) {
    int e4 = (blockIdx.x * blockDim.x + threadIdx.x) * 4;
    if (e4 >= N_EDGES) return;
    int4 dst = *reinterpret_cast<const int4*>(ei + N_EDGES + e4);
    int4 rr  = *reinterpret_cast<const int4*>(et + e4);
    atomicAdd(&bins[dst.x * N_REL + rr.x], 1);
    atomicAdd(&bins[dst.y * N_REL + rr.y], 1);
    atomicAdd(&bins[dst.z * N_REL + rr.z], 1);
    atomicAdd(&bins[dst.w * N_REL + rr.w], 1);
}

__global__ __launch_bounds__(256) void scanA_kernel(const int* __restrict__ bins,
                                                    int* __restrict__ ptr,
                                                    int* __restrict__ bsum) {
    __shared__ int wsum[4];
    int t    = threadIdx.x;
    int base = blockIdx.x * 1024 + t * 4;
    int v[4];
#pragma unroll
    for (int i = 0; i < 4; ++i) {
        int idx = base + i;
        v[i] = (idx < NBINS) ? bins[idx] : 0;
    }
    int tot  = v[0] + v[1] + v[2] + v[3];
    int lane = t & 63, w = t >> 6;
    int inc  = tot;
#pragma unroll
    for (int d = 1; d < 64; d <<= 1) {
        int n = __shfl_up(inc, d);
        if (lane >= d) inc += n;
    }
    if (lane == 63) wsum[w] = inc;
    __syncthreads();
    int woff = 0;
    for (int i = 0; i < w; ++i) woff += wsum[i];
    int run = woff + inc - tot;
#pragma unroll
    for (int i = 0; i < 4; ++i) {
        int idx = base + i;
        if (idx < NBINS) ptr[idx] = run;
        run += v[i];
    }
    if (t == 255) bsum[blockIdx.x] = woff + inc;
}

__global__ __launch_bounds__(256) void scanB_kernel(const int* __restrict__ bsum,
                                                    int* __restrict__ boff, int nblk) {
    __shared__ int sh[256];
    int t = threadIdx.x;
    int v = (t < nblk) ? bsum[t] : 0;
    sh[t] = v;
    __syncthreads();
    for (int d = 1; d < 256; d <<= 1) {
        int n = (t >= d) ? sh[t - d] : 0;
        __syncthreads();
        sh[t] += n;
        __syncthreads();
    }
    if (t < nblk) boff[t] = sh[t] - v;
}

__global__ __launch_bounds__(256) void scanC_kernel(int* __restrict__ ptr,
                                                    int* __restrict__ cur,
                                                    const int* __restrict__ boff) {
    int base = blockIdx.x * 1024 + threadIdx.x * 4;
    int off  = boff[blockIdx.x];
#pragma unroll
    for (int i = 0; i < 4; ++i) {
        int idx = base + i;
        if (idx < NBINS) {
            int p = ptr[idx] + off;
            ptr[idx] = p;
            cur[idx] = p;
        }
    }
    if (blockIdx.x == 0 && threadIdx.x == 0) ptr[NBINS] = N_EDGES;
}

__global__ __launch_bounds__(256) void scatter_kernel(const int* __restrict__ ei,
                                                      const int* __restrict__ et,
                                                      int* __restrict__ cur,
                                                      int* __restrict__ perm) {
    int e4 = (blockIdx.x * blockDim.x + threadIdx.x) * 4;
    if (e4 >= N_EDGES) return;
    int4 src = *reinterpret_cast<const int4*>(ei + e4);
    int4 dst = *reinterpret_cast<const int4*>(ei + N_EDGES + e4);
    int4 rr  = *reinterpret_cast<const int4*>(et + e4);
    int p0 = atomicAdd(&cur[dst.x * N_REL + rr.x], 1);
    int p1 = atomicAdd(&cur[dst.y * N_REL + rr.y], 1);
    int p2 = atomicAdd(&cur[dst.z * N_REL + rr.z], 1);
    int p3 = atomicAdd(&cur[dst.w * N_REL + rr.w], 1);
    perm[p0] = src.x;
    perm[p1] = src.y;
    perm[p2] = src.z;
    perm[p3] = src.w;
}

// ============ fp32 -> bf16 shadow copy (for the layer-1 gather) ============
__global__ __launch_bounds__(256) void cvt_kernel(const float* __restrict__ in,
                                                  unsigned short* __restrict__ out) {
    int i = blockIdx.x * blockDim.x + threadIdx.x;   // per 4 elems
    float4 v = *reinterpret_cast<const float4*>(in + (size_t)i * 4);
    ushort4 o;
    o.x = (unsigned short)f2bf(v.x); o.y = (unsigned short)f2bf(v.y);
    o.z = (unsigned short)f2bf(v.z); o.w = (unsigned short)f2bf(v.w);
    *reinterpret_cast<ushort4*>(out + (size_t)i * 4) = o;
}

// ============ segmented mean-aggregation: S[n,r,:] = mean Xb[src] ============
// bf16 gather (256B/edge), fp32 accumulate, bf16 S output (half the write).
__global__ __launch_bounds__(256) void agg_csr_kernel(const unsigned short* __restrict__ Xb,
                                                      const int* __restrict__ ptr,
                                                      const int* __restrict__ perm,
                                                      unsigned short* __restrict__ S) {
    int node = blockIdx.x * 4 + (threadIdx.x >> 6);
    int l    = threadIdx.x & 63;

    int pr[5];
#pragma unroll
    for (int i = 0; i < 5; ++i) pr[i] = ptr[node * 4 + i];

    int wbase = pr[0];
    int srcs  = perm[min(wbase + l, N_EDGES - 1)];
    unsigned short* Sp = S + (size_t)node * 512 + l * 2;

#pragma unroll
    for (int r = 0; r < 4; ++r) {
        int s = pr[r], e = pr[r + 1];
        float ax = 0.f, ay = 0.f;
        for (int j = s; j < e; j += 4) {
            int hi = min(j + 3, e - 1);
            if (hi >= wbase + 64) {            // wave-uniform window reload
                wbase = j;
                srcs  = perm[min(wbase + l, N_EDGES - 1)];
            }
            ushort2 v[4]; bool val[4];
#pragma unroll
            for (int u = 0; u < 4; ++u) {
                int jj = j + u;
                val[u] = jj < e;
                int src = __shfl(srcs, (val[u] ? jj : j) - wbase);
                v[u] = *reinterpret_cast<const ushort2*>(Xb + (size_t)src * 128 + l * 2);
            }
#pragma unroll
            for (int u = 0; u < 4; ++u) {
                ax += val[u] ? bf2f((short)v[u].x) : 0.f;
                ay += val[u] ? bf2f((short)v[u].y) : 0.f;
            }
        }
        float sc = 1.0f / (float)max(e - s, 1);
        ushort2 o;
        o.x = (unsigned short)f2bf(ax * sc);
        o.y = (unsigned short)f2bf(ay * sc);
        *reinterpret_cast<ushort2*>(Sp + (size_t)r * 128) = o;
    }
}

// ============ weight prep: W^T, split into bf16 hi/lo: Wt[col][640] ============
__global__ __launch_bounds__(256) void prep_w(const float* __restrict__ Wroot,
                                              const float* __restrict__ Wrel,
                                              short* __restrict__ Wth,
                                              short* __restrict__ Wtl) {
    int col = blockIdx.x;                       // 0..127
    for (int g = threadIdx.x; g < KTOT; g += 256) {
        float w = (g < 128) ? Wroot[(size_t)g * 128 + col]
                            : Wrel[(size_t)(g - 128) * 128 + col];
        short h  = f2bf(w);
        short lo = f2bf(w - bf2f(h));
        Wth[(size_t)col * KTOT + g] = h;
        Wtl[(size_t)col * KTOT + g] = lo;
    }
}

// ============ fused layer GEMM via split-bf16 MFMA ============
// C = X@Wroot + b + sum_r S[:,r]@Wrel[r].  X fp32 (hi/lo split, 3 MFMAs);
// S bf16 (hi only, 2 MFMAs).  Optional relu; optional dual bf16 output.
__global__ __launch_bounds__(256, 3) void gemm_layer_mfma(
        const float* __restrict__ X, const unsigned short* __restrict__ S,
        const short* __restrict__ Wth, const short* __restrict__ Wtl,
        const float* __restrict__ bias, float* __restrict__ C,
        unsigned short* __restrict__ Cb, int relu_out) {
    __shared__ __align__(16) short As_h[64 * 64];    //  8 KB
    __shared__ __align__(16) short As_l[64 * 64];    //  8 KB
    __shared__ __align__(16) short Bs_h[128 * 64];   // 16 KB  [col][k]
    __shared__ __align__(16) short Bs_l[128 * 64];   // 16 KB

    const int t   = threadIdx.x;
    const int rm  = blockIdx.x * 64;
    const int l   = t & 63, w = t >> 6;
    const int mh  = (w >> 1) * 32;        // wave row-half
    const int nh  = (w & 1) * 64;         // wave col-half
    const int r16 = l & 15, kch = l >> 4; // MFMA lane coords

    f32x4 acc[2][4];
#pragma unroll
    for (int mt = 0; mt < 2; ++mt)
#pragma unroll
        for (int nt = 0; nt < 4; ++nt)
            acc[mt][nt] = (f32x4){0.f, 0.f, 0.f, 0.f};

    for (int kt = 0; kt < 10; ++kt) {
        const bool xpart = (kt < 2);
        // ---- stage A ----
        if (xpart) {
            // 64 rows x 64 k fp32 -> bf16 hi/lo, swizzled
#pragma unroll
            for (int i = 0; i < 4; ++i) {
                int idx  = t + i * 256;        // 0..1023
                int row  = idx >> 4;           // 0..63
                int kc   = (idx & 15) * 4;     // 0..60
                int grow = rm + row;
                float4 v = *reinterpret_cast<const float4*>(X + (size_t)grow * 128 + kt * 64 + kc);
                short h0 = f2bf(v.x), h1 = f2bf(v.y), h2 = f2bf(v.z), h3 = f2bf(v.w);
                short l0 = f2bf(v.x - bf2f(h0)), l1 = f2bf(v.y - bf2f(h1));
                short l2 = f2bf(v.z - bf2f(h2)), l3 = f2bf(v.w - bf2f(h3));
                int off = ((row << 7) + (kc << 1)) ^ ((row & 7) << 4);
                *reinterpret_cast<short4*>((char*)As_h + off) = make_short4(h0, h1, h2, h3);
                *reinterpret_cast<short4*>((char*)As_l + off) = make_short4(l0, l1, l2, l3);
            }
        } else {
            // 64 rows x 64 k bf16 direct, swizzled (no conversion, no lo)
#pragma unroll
            for (int i = 0; i < 2; ++i) {
                int idx  = t + i * 256;        // 0..511
                int row  = idx >> 3;           // 0..63
                int k0   = (idx & 7) * 8;      // 0..56
                int grow = rm + row;
                bf16x8 v = *reinterpret_cast<const bf16x8*>(
                    S + (size_t)grow * 512 + (kt - 2) * 64 + k0);
                int off = ((row << 7) + (k0 << 1)) ^ ((row & 7) << 4);
                *reinterpret_cast<bf16x8*>((char*)As_h + off) = v;
            }
        }
        // ---- stage B: 128 cols x 64 k from pre-split W^T, swizzled ----
#pragma unroll
        for (int i = 0; i < 4; ++i) {
            int idx = t + i * 256;         // 0..1023
            int col = idx >> 3;            // 0..127
            int k0  = (idx & 7) * 8;       // 0..56
            size_t goff = (size_t)col * KTOT + kt * 64 + k0;
            bf16x8 hv = *reinterpret_cast<const bf16x8*>(Wth + goff);
            bf16x8 lv = *reinterpret_cast<const bf16x8*>(Wtl + goff);
            int off = ((col << 7) + (k0 << 1)) ^ ((col & 7) << 4);
            *reinterpret_cast<bf16x8*>((char*)Bs_h + off) = hv;
            *reinterpret_cast<bf16x8*>((char*)Bs_l + off) = lv;
        }
        __syncthreads();
        // ---- 2 x K32 MFMA steps ----
#pragma unroll
        for (int s = 0; s < 2; ++s) {
            int kb = s * 64 + kch * 16;    // byte offset of this lane's k-chunk
            bf16x8 ah[2], al[2], bh[4], bl[4];
#pragma unroll
            for (int mt = 0; mt < 2; ++mt) {
                int row = mh + mt * 16 + r16;
                int off = ((row << 7) + kb) ^ ((row & 7) << 4);
                ah[mt] = *reinterpret_cast<const bf16x8*>((const char*)As_h + off);
                if (xpart)
                    al[mt] = *reinterpret_cast<const bf16x8*>((const char*)As_l + off);
            }
#pragma unroll
            for (int nt = 0; nt < 4; ++nt) {
                int col = nh + nt * 16 + r16;
                int off = ((col << 7) + kb) ^ ((col & 7) << 4);
                bh[nt] = *reinterpret_cast<const bf16x8*>((const char*)Bs_h + off);
                bl[nt] = *reinterpret_cast<const bf16x8*>((const char*)Bs_l + off);
            }
#pragma unroll
            for (int mt = 0; mt < 2; ++mt)
#pragma unroll
                for (int nt = 0; nt < 4; ++nt) {
                    acc[mt][nt] = __builtin_amdgcn_mfma_f32_16x16x32_bf16(ah[mt], bh[nt], acc[mt][nt], 0, 0, 0);
                    acc[mt][nt] = __builtin_amdgcn_mfma_f32_16x16x32_bf16(ah[mt], bl[nt], acc[mt][nt], 0, 0, 0);
                    if (xpart)
                        acc[mt][nt] = __builtin_amdgcn_mfma_f32_16x16x32_bf16(al[mt], bh[nt], acc[mt][nt], 0, 0, 0);
                }
        }
        __syncthreads();
    }
    // ---- epilogue: C/D layout col=l&15, row=(l>>4)*4+r ----
#pragma unroll
    for (int mt = 0; mt < 2; ++mt)
#pragma unroll
        for (int nt = 0; nt < 4; ++nt) {
            int col = nh + nt * 16 + r16;
            float bv = bias[col];
#pragma unroll
            for (int r = 0; r < 4; ++r) {
                int row = rm + mh + mt * 16 + kch * 4 + r;
                float o = acc[mt][nt][r] + bv;
                if (relu_out) o = fmaxf(o, 0.f);
                C[(size_t)row * 128 + col] = o;
                if (Cb) Cb[(size_t)row * 128 + col] = (unsigned short)f2bf(o);
            }
        }
}

// ========== head GEMM (fp32): gather(nest,food) fused, relu out ==========
#define FMA16()                                                                 \
    acc[0][0] = fmaf(a0, b.x, acc[0][0]); acc[0][1] = fmaf(a0, b.y, acc[0][1]); \
    acc[0][2] = fmaf(a0, b.z, acc[0][2]); acc[0][3] = fmaf(a0, b.w, acc[0][3]); \
    acc[1][0] = fmaf(a1, b.x, acc[1][0]); acc[1][1] = fmaf(a1, b.y, acc[1][1]); \
    acc[1][2] = fmaf(a1, b.z, acc[1][2]); acc[1][3] = fmaf(a1, b.w, acc[1][3]); \
    acc[2][0] = fmaf(a2, b.x, acc[2][0]); acc[2][1] = fmaf(a2, b.y, acc[2][1]); \
    acc[2][2] = fmaf(a2, b.z, acc[2][2]); acc[2][3] = fmaf(a2, b.w, acc[2][3]); \
    acc[3][0] = fmaf(a3, b.x, acc[3][0]); acc[3][1] = fmaf(a3, b.y, acc[3][1]); \
    acc[3][2] = fmaf(a3, b.z, acc[3][2]); acc[3][3] = fmaf(a3, b.w, acc[3][3])

#define KSTEP(J, AX)                                                \
    {                                                               \
        float4 b  = bq##J;                                          \
        float  a0 = aq0.AX, a1 = aq1.AX, a2 = aq2.AX, a3 = aq3.AX;  \
        FMA16();                                                    \
    }

#define INNER_K128(AS, BS)                                                     \
    _Pragma("unroll 2")                                                        \
    for (int kk = 0; kk < 128; kk += 4) {                                      \
        float4 aq0 = *reinterpret_cast<const float4*>(&AS[ty * 4 + 0][kk]);    \
        float4 aq1 = *reinterpret_cast<const float4*>(&AS[ty * 4 + 1][kk]);    \
        float4 aq2 = *reinterpret_cast<const float4*>(&AS[ty * 4 + 2][kk]);    \
        float4 aq3 = *reinterpret_cast<const float4*>(&AS[ty * 4 + 3][kk]);    \
        float4 bq0 = *reinterpret_cast<const float4*>(&BS[kk + 0][tx * 4]);    \
        float4 bq1 = *reinterpret_cast<const float4*>(&BS[kk + 1][tx * 4]);    \
        float4 bq2 = *reinterpret_cast<const float4*>(&BS[kk + 2][tx * 4]);    \
        float4 bq3 = *reinterpret_cast<const float4*>(&BS[kk + 3][tx * 4]);    \
        KSTEP(0, x); KSTEP(1, y); KSTEP(2, z); KSTEP(3, w);                    \
    }

__global__ __launch_bounds__(256) void gemm_head(const float* __restrict__ H,
                                                 const int* __restrict__ nest,
                                                 const int* __restrict__ food,
                                                 const float* __restrict__ W,
                                                 const float* __restrict__ bias,
                                                 float* __restrict__ C) {
    __shared__ __align__(16) float As[64][132];
    __shared__ __align__(16) float Bs[128][68];
    int t  = threadIdx.x;
    int rm = blockIdx.x * 64;
    int cn = blockIdx.y * 64;
    int ty = t >> 4, tx = t & 15;
    float acc[4][4];
#pragma unroll
    for (int i = 0; i < 4; ++i)
#pragma unroll
        for (int j = 0; j < 4; ++j) acc[i][j] = 0.f;

    for (int kt = 0; kt < 2; ++kt) {
        const int* idx = (kt == 0) ? nest : food;
#pragma unroll
        for (int i = 0; i < 8; ++i) {
            int idx4 = t + i * 256;
            int row  = idx4 >> 5;
            int kc4  = idx4 & 31;
            int node = idx[rm + row];
            *reinterpret_cast<float4*>(&As[row][kc4 * 4]) =
                *reinterpret_cast<const float4*>(H + (size_t)node * 128 + kc4 * 4);
        }
#pragma unroll
        for (int i = 0; i < 8; ++i) {
            int idx4 = t + i * 256;
            int kk   = idx4 >> 4;
            int j4   = idx4 & 15;
            *reinterpret_cast<float4*>(&Bs[kk][j4 * 4]) =
                *reinterpret_cast<const float4*>(W + (size_t)(kt * 128 + kk) * 256 + cn + j4 * 4);
        }
        __syncthreads();
        INNER_K128(As, Bs);
        __syncthreads();
    }
    float4 bv = *reinterpret_cast<const float4*>(bias + cn + tx * 4);
#pragma unroll
    for (int i = 0; i < 4; ++i) {
        int grow = rm + ty * 4 + i;
        float4 o;
        o.x = fmaxf(acc[i][0] + bv.x, 0.f); o.y = fmaxf(acc[i][1] + bv.y, 0.f);
        o.z = fmaxf(acc[i][2] + bv.z, 0.f); o.w = fmaxf(acc[i][3] + bv.w, 0.f);
        *reinterpret_cast<float4*>(C + (size_t)grow * 256 + cn + tx * 4) = o;
    }
}

// ====== heads: logits + log_softmax + dist, one wave per query ======
__global__ __launch_bounds__(256) void head_kernel(const float* __restrict__ hidden,
                                                   const float* __restrict__ dirW,
                                                   const float* __restrict__ dirB,
                                                   const float* __restrict__ distW,
                                                   const float* __restrict__ distB,
                                                   float* __restrict__ outA,
                                                   float* __restrict__ outB) {
    __shared__ __align__(16) float sm[4][256];
    int t = threadIdx.x;
    int w = t >> 6;
    int l = t & 63;
    int q = blockIdx.x * 4 + w;

    float4 hv = *reinterpret_cast<const float4*>(hidden + (size_t)q * 256 + l * 4);
    *reinterpret_cast<float4*>(&sm[w][l * 4]) = hv;
    __syncthreads();

    int v  = l & 15;
    int kc = l >> 4;
    float p = 0.f;
#pragma unroll
    for (int i = 0; i < 64; ++i) {
        int k = kc * 64 + i;
        p = fmaf(sm[w][k], dirW[k * VOCAB + v], p);
    }
    p += __shfl_xor(p, 16);
    p += __shfl_xor(p, 32);
    p += dirB[v];

    float m = p;
#pragma unroll
    for (int d = 1; d < 16; d <<= 1) m = fmaxf(m, __shfl_xor(m, d));
    float es = __expf(p - m);
    float ss = es;
#pragma unroll
    for (int d = 1; d < 16; d <<= 1) ss += __shfl_xor(ss, d);
    float outv = p - m - __logf(ss);
    if (l < 16) outA[(size_t)q * VOCAB + v] = outv;

    float pd = hv.x * distW[l * 4 + 0] + hv.y * distW[l * 4 + 1] +
               hv.z * distW[l * 4 + 2] + hv.w * distW[l * 4 + 3];
#pragma unroll
    for (int d = 1; d < 64; d <<= 1) pd += __shfl_xor(pd, d);
    if (l == 0) outB[q] = pd + distB[0];
}

extern "C" void kernel_launch(void* const* d_in, const int* in_sizes, int n_in,
                              void* d_out, int out_size, void* d_ws, size_t ws_size,
                              hipStream_t stream) {
    const float* x      = (const float*)d_in[0];
    const int*   ei     = (const int*)d_in[1];
    const int*   et     = (const int*)d_in[2];
    const int*   nest   = (const int*)d_in[3];
    const int*   food   = (const int*)d_in[4];
    const float* Wrel1  = (const float*)d_in[5];
    const float* Wroot1 = (const float*)d_in[6];
    const float* b1     = (const float*)d_in[7];
    const float* Wrel2  = (const float*)d_in[8];
    const float* Wroot2 = (const float*)d_in[9];
    const float* b2     = (const float*)d_in[10];
    const float* fcW    = (const float*)d_in[11];
    const float* fcB    = (const float*)d_in[12];
    const float* dirW   = (const float*)d_in[13];
    const float* dirB   = (const float*)d_in[14];
    const float* distW  = (const float*)d_in[15];
    const float* distB  = (const float*)d_in[16];

    char* ws = (char*)d_ws;
    size_t off = 0;
    auto alloc = [&](size_t bytes) {
        void* p = ws + off;
        off += (bytes + 255) & ~(size_t)255;
        return p;
    };
    unsigned short* S = (unsigned short*)alloc((size_t)N_NODES * 512 * 2);  // 40.96 MB (bf16)
    float* hA     = (float*)alloc((size_t)N_NODES * 128 * 4);   // 20.48 MB
    float* hB     = (float*)alloc((size_t)N_NODES * 128 * 4);   // 20.48 MB
    float* hidden = (float*)alloc((size_t)NB * 256 * 4);        //  4.19 MB
    // wtbuf aliases the bins histogram (bins dead after scanA; prep_w runs after scatter)
    short* wtbuf  = (short*)alloc((size_t)4 * 128 * KTOT * 2);  // 0.655 MB
    int*   bins   = (int*)wtbuf;                                // needs 0.64 MB
    int*   ptr    = (int*)alloc((size_t)(NBINS + 1) * 4);
    int*   cur    = (int*)alloc((size_t)(NBINS + 1) * 4);
    int*   bsum   = (int*)alloc(256 * 4);
    int*   boff   = (int*)alloc(256 * 4);
    int*   perm   = (int*)alloc((size_t)N_EDGES * 4);           //  2.56 MB

    // bf16 gather shadow (10.24 MB) aliased over hB: hB is only written by
    // gemm-2, which runs AFTER the last read of the shadow (agg-2).
    unsigned short* xb = (unsigned short*)hB;

    short* wt1h = wtbuf;
    short* wt1l = wtbuf + 128 * KTOT;
    short* wt2h = wtbuf + 2 * 128 * KTOT;
    short* wt2l = wtbuf + 3 * 128 * KTOT;

    float* outA = (float*)d_out;             // [B,16]
    float* outB = (float*)d_out + NB * 16;   // [B]

    const int SCAN_BLKS = (NBINS + 1023) / 1024;       // 157
    const int CVT_BLKS  = (N_NODES * 128 / 4) / 256;   // 5000
    const int E4_BLKS   = (N_EDGES / 4 + 255) / 256;   // 625

    // ---- CSR build (shared by both layers; uses bins region first) ----
    hipMemsetAsync(bins, 0, (size_t)NBINS * 4, stream);
    hist_kernel<<<E4_BLKS, 256, 0, stream>>>(ei, et, bins);
    scanA_kernel<<<SCAN_BLKS, 256, 0, stream>>>(bins, ptr, bsum);
    scanB_kernel<<<1, 256, 0, stream>>>(bsum, boff, SCAN_BLKS);
    scanC_kernel<<<SCAN_BLKS, 256, 0, stream>>>(ptr, cur, boff);
    scatter_kernel<<<E4_BLKS, 256, 0, stream>>>(ei, et, cur, perm);

    // ---- weight prep (overwrites dead bins region) ----
    prep_w<<<128, 256, 0, stream>>>(Wroot1, Wrel1, wt1h, wt1l);
    prep_w<<<128, 256, 0, stream>>>(Wroot2, Wrel2, wt2h, wt2l);

    // ---- layer 1: bf16 shadow of x -> agg -> GEMM (relu, dual fp32+bf16 out) ----
    cvt_kernel<<<CVT_BLKS, 256, 0, stream>>>(x, xb);
    agg_csr_kernel<<<N_NODES / 4, 256, 0, stream>>>(xb, ptr, perm, S);
    gemm_layer_mfma<<<625, 256, 0, stream>>>(x, S, wt1h, wt1l, b1, hA, xb, 1);

    // ---- layer 2: agg(bf16 hA shadow) -> GEMM ----
    agg_csr_kernel<<<N_NODES / 4, 256, 0, stream>>>(xb, ptr, perm, S);
    gemm_layer_mfma<<<625, 256, 0, stream>>>(hA, S, wt2h, wt2l, b2, hB, (unsigned short*)nullptr, 0);

    // ---- heads ----
    gemm_head<<<dim3(64, 4), 256, 0, stream>>>(hB, nest, food, fcW, fcB, hidden);
    head_kernel<<<NB / 4, 256, 0, stream>>>(hidden, dirW, dirB, distW, distB, outA, outB);
}